// Round 1
// baseline (1755.011 us; speedup 1.0000x reference)
//
#include <hip/hip_runtime.h>
#include <hip/hip_bf16.h>
#include <cstdint>

#define Bn 8
#define Tn 512
#define Dn 1024
#define Hn 16
#define DKn 64
#define Mn (Bn * Tn)   // 4096

// ---------------------------------------------------------------------------
// Generic fp32 GEMM: C[M,N] = A[M,K] @ B[K,N] (+bias) (+relu)
// HEADW=1: B is (H, K, 64) per-head slabs, n-tile == head (N tile 64 == DK).
// Tile 64x64x32, 256 threads, 4x4 micro-tile per thread.
// ---------------------------------------------------------------------------
template<int HEADW, int BIAS, int RELU>
__global__ __launch_bounds__(256) void gemm_k(
    const float* __restrict__ A,
    const float* __restrict__ B0, const float* __restrict__ B1, const float* __restrict__ B2,
    const float* __restrict__ bias,
    float* __restrict__ C0, float* __restrict__ C1, float* __restrict__ C2,
    int N, int K)
{
  __shared__ float As[32][68];   // [k][m], padded (272B rows keep 16B align)
  __shared__ float Bs[32][68];   // [k][n], padded

  const float* Bw = B0;
  float* C = C0;
  if (HEADW) {
    if (blockIdx.z == 1) { Bw = B1; C = C1; }
    else if (blockIdx.z == 2) { Bw = B2; C = C2; }
  }

  const int tid = threadIdx.x;
  const int tx = tid & 15;
  const int ty = tid >> 4;
  const int bx = blockIdx.x;
  const int by = blockIdx.y;
  const int m0 = by << 6;
  const int n0 = bx << 6;

  float acc[4][4] = {};

  for (int k0 = 0; k0 < K; k0 += 32) {
    // A tile: 64 rows x 32 k -> 512 float4, 2 per thread
#pragma unroll
    for (int i = 0; i < 2; i++) {
      int idx = (i << 8) + tid;
      int m  = idx >> 3;
      int kq = (idx & 7) << 2;
      float4 av = *reinterpret_cast<const float4*>(&A[(size_t)(m0 + m) * K + k0 + kq]);
      As[kq + 0][m] = av.x;
      As[kq + 1][m] = av.y;
      As[kq + 2][m] = av.z;
      As[kq + 3][m] = av.w;
    }
    // B tile: 32 k x 64 n -> 512 float4, 2 per thread
#pragma unroll
    for (int i = 0; i < 2; i++) {
      int idx = (i << 8) + tid;
      int kk = idx >> 4;
      int c4 = (idx & 15) << 2;
      const float* bp = HEADW
          ? &Bw[((size_t)bx * K + (size_t)(k0 + kk)) * 64 + c4]
          : &Bw[(size_t)(k0 + kk) * N + n0 + c4];
      *reinterpret_cast<float4*>(&Bs[kk][c4]) = *reinterpret_cast<const float4*>(bp);
    }
    __syncthreads();

#pragma unroll
    for (int kk = 0; kk < 32; kk++) {
      float4 av = *reinterpret_cast<const float4*>(&As[kk][ty << 2]);
      float4 bv = *reinterpret_cast<const float4*>(&Bs[kk][tx << 2]);
      float a_[4] = {av.x, av.y, av.z, av.w};
      float b_[4] = {bv.x, bv.y, bv.z, bv.w};
#pragma unroll
      for (int i = 0; i < 4; i++)
#pragma unroll
        for (int j = 0; j < 4; j++)
          acc[i][j] = fmaf(a_[i], b_[j], acc[i][j]);
    }
    __syncthreads();
  }

#pragma unroll
  for (int i = 0; i < 4; i++) {
    int m = m0 + (ty << 2) + i;
    float4 o;
    o.x = acc[i][0]; o.y = acc[i][1]; o.z = acc[i][2]; o.w = acc[i][3];
    if (BIAS) {
      float4 bb = *reinterpret_cast<const float4*>(&bias[n0 + (tx << 2)]);
      o.x += bb.x; o.y += bb.y; o.z += bb.z; o.w += bb.w;
    }
    if (RELU) {
      o.x = fmaxf(o.x, 0.f); o.y = fmaxf(o.y, 0.f);
      o.z = fmaxf(o.z, 0.f); o.w = fmaxf(o.w, 0.f);
    }
    *reinterpret_cast<float4*>(&C[(size_t)m * Dn + n0 + (tx << 2)]) = o;
  }
}

// ---------------------------------------------------------------------------
// Attention: block = (b, h, 16-row q chunk). Scores in LDS, K/V tiles staged.
// q/k/v layout: (B, T, H, DK) flat = (4096, 1024) row-major.
// ---------------------------------------------------------------------------
__global__ __launch_bounds__(256) void attn_k(
    const float* __restrict__ q, const float* __restrict__ kx,
    const float* __restrict__ vx, float* __restrict__ o)
{
  const int tc = blockIdx.x;   // 0..31
  const int h  = blockIdx.y;   // 0..15
  const int b  = blockIdx.z;   // 0..7
  const int tid = threadIdx.x;

  __shared__ float Qs[16][68];
  __shared__ float S[16][516];
  __shared__ float KV[128][66];

  const int t0 = tc << 4;
  const size_t qbase  = ((size_t)(b * Tn + t0) * Dn) + h * DKn;
  const size_t kvbase = ((size_t)(b * Tn) * Dn) + h * DKn;

  // load Q (16 x 64)
  {
    int r  = tid >> 4;
    int c4 = (tid & 15) << 2;
    float4 qv = *reinterpret_cast<const float4*>(&q[qbase + (size_t)r * Dn + c4]);
    Qs[r][c4 + 0] = qv.x; Qs[r][c4 + 1] = qv.y;
    Qs[r][c4 + 2] = qv.z; Qs[r][c4 + 3] = qv.w;
  }

  // Phase 1: scores S[r][s] = (q_r . k_s) / 8
  for (int st = 0; st < 4; st++) {
    __syncthreads();   // KV reuse / Qs ready
#pragma unroll
    for (int i = 0; i < 8; i++) {
      int idx = (i << 8) + tid;
      int sr = idx >> 4;
      int c4 = (idx & 15) << 2;
      float4 kv4 = *reinterpret_cast<const float4*>(
          &kx[kvbase + (size_t)((st << 7) + sr) * Dn + c4]);
      KV[sr][c4 + 0] = kv4.x; KV[sr][c4 + 1] = kv4.y;
      KV[sr][c4 + 2] = kv4.z; KV[sr][c4 + 3] = kv4.w;
    }
    __syncthreads();
#pragma unroll
    for (int i = 0; i < 8; i++) {
      int idx = (i << 8) + tid;
      int r  = idx >> 7;
      int sl = idx & 127;
      float acc = 0.f;
#pragma unroll
      for (int d = 0; d < 64; d++) acc = fmaf(Qs[r][d], KV[sl][d], acc);
      S[r][(st << 7) + sl] = acc * 0.125f;
    }
  }
  __syncthreads();

  // Phase 2: softmax per row (16 lanes per row)
  {
    int r = tid >> 4;
    int g = tid & 15;
    float mx = -1e30f;
#pragma unroll
    for (int i = 0; i < 32; i++) mx = fmaxf(mx, S[r][g + (i << 4)]);
#pragma unroll
    for (int msk = 1; msk < 16; msk <<= 1) mx = fmaxf(mx, __shfl_xor(mx, msk, 64));
    float sum = 0.f;
#pragma unroll
    for (int i = 0; i < 32; i++) {
      float e = __expf(S[r][g + (i << 4)] - mx);
      S[r][g + (i << 4)] = e;
      sum += e;
    }
#pragma unroll
    for (int msk = 1; msk < 16; msk <<= 1) sum += __shfl_xor(sum, msk, 64);
    float inv = 1.f / sum;
#pragma unroll
    for (int i = 0; i < 32; i++) S[r][g + (i << 4)] *= inv;
  }
  __syncthreads();

  // Phase 3: O = W @ V
  float accO[4] = {0.f, 0.f, 0.f, 0.f};
  const int dk = tid & 63;
  const int rg = tid >> 6;
  for (int st = 0; st < 4; st++) {
#pragma unroll
    for (int i = 0; i < 8; i++) {
      int idx = (i << 8) + tid;
      int sr = idx >> 4;
      int c4 = (idx & 15) << 2;
      float4 v4 = *reinterpret_cast<const float4*>(
          &vx[kvbase + (size_t)((st << 7) + sr) * Dn + c4]);
      KV[sr][c4 + 0] = v4.x; KV[sr][c4 + 1] = v4.y;
      KV[sr][c4 + 2] = v4.z; KV[sr][c4 + 3] = v4.w;
    }
    __syncthreads();
#pragma unroll 8
    for (int sl = 0; sl < 128; sl++) {
      float vv = KV[sl][dk];
#pragma unroll
      for (int j = 0; j < 4; j++)
        accO[j] = fmaf(S[rg + (j << 2)][(st << 7) + sl], vv, accO[j]);
    }
    __syncthreads();
  }
#pragma unroll
  for (int j = 0; j < 4; j++) {
    int r = rg + (j << 2);
    o[qbase + (size_t)r * Dn + dk] = accO[j];
  }
}

// ---------------------------------------------------------------------------
// r = a + b (elementwise), plus per-block partial column sums / sumsq.
// Block = 16 rows; thread owns 4 consecutive cols (float4).
// ---------------------------------------------------------------------------
__global__ __launch_bounds__(256) void add_stats_k(
    const float* __restrict__ a, const float* __restrict__ b,
    float* __restrict__ r, float* __restrict__ ps, float* __restrict__ pq)
{
  const int blk = blockIdx.x;
  const int tid = threadIdx.x;
  const int c4 = tid << 2;
  const int row0 = blk << 4;
  float s0 = 0, s1 = 0, s2 = 0, s3 = 0;
  float q0 = 0, q1 = 0, q2 = 0, q3 = 0;
#pragma unroll 4
  for (int i = 0; i < 16; i++) {
    size_t off = (size_t)(row0 + i) * Dn + c4;
    float4 av = *reinterpret_cast<const float4*>(&a[off]);
    float4 bv = *reinterpret_cast<const float4*>(&b[off]);
    float4 rv = make_float4(av.x + bv.x, av.y + bv.y, av.z + bv.z, av.w + bv.w);
    *reinterpret_cast<float4*>(&r[off]) = rv;
    s0 += rv.x; q0 = fmaf(rv.x, rv.x, q0);
    s1 += rv.y; q1 = fmaf(rv.y, rv.y, q1);
    s2 += rv.z; q2 = fmaf(rv.z, rv.z, q2);
    s3 += rv.w; q3 = fmaf(rv.w, rv.w, q3);
  }
  size_t po = (size_t)blk * Dn + c4;
  *reinterpret_cast<float4*>(&ps[po]) = make_float4(s0, s1, s2, s3);
  *reinterpret_cast<float4*>(&pq[po]) = make_float4(q0, q1, q2, q3);
}

// 1024 cols total; 4 blocks x 256 threads; reduce 256 partials -> scale/shift
__global__ __launch_bounds__(256) void reduce_stats_k(
    const float* __restrict__ ps, const float* __restrict__ pq,
    const float* __restrict__ g, const float* __restrict__ be,
    float* __restrict__ scale, float* __restrict__ shift)
{
  const int col = blockIdx.x * 256 + threadIdx.x;
  float s = 0.f, q = 0.f;
  for (int p = 0; p < 256; p++) {
    s += ps[(size_t)p * Dn + col];
    q += pq[(size_t)p * Dn + col];
  }
  const float invn = 1.f / 4096.f;
  float mean = s * invn;
  float var = q * invn - mean * mean;
  float inv = rsqrtf(var + 1e-3f);
  float sc = g[col] * inv;
  scale[col] = sc;
  shift[col] = be[col] - mean * sc;
}

__global__ __launch_bounds__(256) void norm_k(
    const float* __restrict__ r, const float* __restrict__ scale,
    const float* __restrict__ shift, float* __restrict__ o)
{
  const int idx = blockIdx.x * 256 + threadIdx.x;   // float4 index
  const int c4 = (idx & 255) << 2;
  float4 rv = *reinterpret_cast<const float4*>(&r[(size_t)idx << 2]);
  float4 sc = *reinterpret_cast<const float4*>(&scale[c4]);
  float4 sh = *reinterpret_cast<const float4*>(&shift[c4]);
  float4 ov = make_float4(fmaf(rv.x, sc.x, sh.x), fmaf(rv.y, sc.y, sh.y),
                          fmaf(rv.z, sc.z, sh.z), fmaf(rv.w, sc.w, sh.w));
  *reinterpret_cast<float4*>(&o[(size_t)idx << 2]) = ov;
}

// ---------------------------------------------------------------------------
extern "C" void kernel_launch(void* const* d_in, const int* in_sizes, int n_in,
                              void* d_out, int out_size, void* d_ws, size_t ws_size,
                              hipStream_t stream)
{
  const float* x   = (const float*)d_in[0];
  const float* wq  = (const float*)d_in[1];
  const float* wk  = (const float*)d_in[2];
  const float* wv  = (const float*)d_in[3];
  const float* W   = (const float*)d_in[4];
  const float* W1  = (const float*)d_in[5];
  const float* b1  = (const float*)d_in[6];
  const float* W2  = (const float*)d_in[7];
  const float* b2  = (const float*)d_in[8];
  const float* g1  = (const float*)d_in[9];
  const float* be1 = (const float*)d_in[10];
  const float* g2  = (const float*)d_in[11];
  const float* be2 = (const float*)d_in[12];

  float* out = (float*)d_out;
  float* ws  = (float*)d_ws;

  const size_t NB = (size_t)Mn * Dn;     // 4M floats
  float* ws0 = ws;
  float* ws1 = ws + NB;
  float* ws2 = ws + 2 * NB;
  float* psum   = ws + 3 * NB;
  float* psumsq = psum + 256 * Dn;
  float* scale  = psumsq + 256 * Dn;
  float* shift  = scale + Dn;

  dim3 blk(256);
  dim3 gemm_grid(Dn / 64, Mn / 64, 1);
  dim3 qkv_grid(Dn / 64, Mn / 64, 3);

  // 1. q,k,v projections -> ws0, ws1, ws2
  gemm_k<1, 0, 0><<<qkv_grid, blk, 0, stream>>>(x, wq, wk, wv, nullptr,
                                                ws0, ws1, ws2, Dn, Dn);
  // 2. attention concat -> d_out (scratch)
  attn_k<<<dim3(Tn / 16, Hn, Bn), blk, 0, stream>>>(ws0, ws1, ws2, out);
  // 3. out = concat @ W -> ws0
  gemm_k<0, 0, 0><<<gemm_grid, blk, 0, stream>>>(out, W, nullptr, nullptr, nullptr,
                                                 ws0, nullptr, nullptr, Dn, Dn);
  // 4. r1 = x + out -> ws1 (+ stats)
  add_stats_k<<<dim3(Mn / 16), blk, 0, stream>>>(x, ws0, ws1, psum, psumsq);
  reduce_stats_k<<<dim3(4), blk, 0, stream>>>(psum, psumsq, g1, be1, scale, shift);
  // 5. out1 -> ws2
  norm_k<<<dim3(NB / 1024), blk, 0, stream>>>(ws1, scale, shift, ws2);
  // 6. h = relu(out1 @ W1 + b1) -> d_out (scratch)
  gemm_k<0, 1, 1><<<gemm_grid, blk, 0, stream>>>(ws2, W1, nullptr, nullptr, b1,
                                                 out, nullptr, nullptr, Dn, Dn);
  // 7. out2 = h @ W2 + b2 -> ws0
  gemm_k<0, 1, 0><<<gemm_grid, blk, 0, stream>>>(out, W2, nullptr, nullptr, b2,
                                                 ws0, nullptr, nullptr, Dn, Dn);
  // 8. r2 = out1 + out2 -> ws1 (+ stats)
  add_stats_k<<<dim3(Mn / 16), blk, 0, stream>>>(ws2, ws0, ws1, psum, psumsq);
  reduce_stats_k<<<dim3(4), blk, 0, stream>>>(psum, psumsq, g2, be2, scale, shift);
  // 9. final BN -> d_out
  norm_k<<<dim3(NB / 1024), blk, 0, stream>>>(ws1, scale, shift, out);
}

// Round 2
// 848.397 us; speedup vs baseline: 2.0686x; 2.0686x over previous
//
#include <hip/hip_runtime.h>
#include <hip/hip_bf16.h>
#include <cstdint>

#define Bn 8
#define Tn 512
#define Dn 1024
#define Hn 16
#define DKn 64
#define Mn (Bn * Tn)   // 4096

typedef short bf16x8 __attribute__((ext_vector_type(8)));
typedef float f32x4 __attribute__((ext_vector_type(4)));

__device__ __forceinline__ unsigned short f2bf(float f) {
  unsigned int u = __builtin_bit_cast(unsigned int, f);
  u += 0x7fffu + ((u >> 16) & 1u);
  return (unsigned short)(u >> 16);
}
__device__ __forceinline__ unsigned int pack2bf(float lo, float hi) {
  return (unsigned int)f2bf(lo) | ((unsigned int)f2bf(hi) << 16);
}
__device__ __forceinline__ bf16x8 cvt8(float4 a, float4 b) {
  union { unsigned int u[4]; bf16x8 v; } r;
  r.u[0] = pack2bf(a.x, a.y);
  r.u[1] = pack2bf(a.z, a.w);
  r.u[2] = pack2bf(b.x, b.y);
  r.u[3] = pack2bf(b.z, b.w);
  return r.v;
}

// ---------------------------------------------------------------------------
// Generic fp32 GEMM: C[M,N] = A[M,K] @ B[K,N] (+bias) (+relu)
// HEADW=1: B is (H, K, 64) per-head slabs, n-tile == head (N tile 64 == DK).
// Tile 64x64x32, 256 threads, 4x4 micro-tile per thread.
// ---------------------------------------------------------------------------
template<int HEADW, int BIAS, int RELU>
__global__ __launch_bounds__(256) void gemm_k(
    const float* __restrict__ A,
    const float* __restrict__ B0, const float* __restrict__ B1, const float* __restrict__ B2,
    const float* __restrict__ bias,
    float* __restrict__ C0, float* __restrict__ C1, float* __restrict__ C2,
    int N, int K)
{
  __shared__ float As[32][68];   // [k][m], padded
  __shared__ float Bs[32][68];   // [k][n], padded

  const float* Bw = B0;
  float* C = C0;
  if (HEADW) {
    if (blockIdx.z == 1) { Bw = B1; C = C1; }
    else if (blockIdx.z == 2) { Bw = B2; C = C2; }
  }

  const int tid = threadIdx.x;
  const int tx = tid & 15;
  const int ty = tid >> 4;
  const int bx = blockIdx.x;
  const int by = blockIdx.y;
  const int m0 = by << 6;
  const int n0 = bx << 6;

  float acc[4][4] = {};

  for (int k0 = 0; k0 < K; k0 += 32) {
#pragma unroll
    for (int i = 0; i < 2; i++) {
      int idx = (i << 8) + tid;
      int m  = idx >> 3;
      int kq = (idx & 7) << 2;
      float4 av = *reinterpret_cast<const float4*>(&A[(size_t)(m0 + m) * K + k0 + kq]);
      As[kq + 0][m] = av.x;
      As[kq + 1][m] = av.y;
      As[kq + 2][m] = av.z;
      As[kq + 3][m] = av.w;
    }
#pragma unroll
    for (int i = 0; i < 2; i++) {
      int idx = (i << 8) + tid;
      int kk = idx >> 4;
      int c4 = (idx & 15) << 2;
      const float* bp = HEADW
          ? &Bw[((size_t)bx * K + (size_t)(k0 + kk)) * 64 + c4]
          : &Bw[(size_t)(k0 + kk) * N + n0 + c4];
      *reinterpret_cast<float4*>(&Bs[kk][c4]) = *reinterpret_cast<const float4*>(bp);
    }
    __syncthreads();

#pragma unroll
    for (int kk = 0; kk < 32; kk++) {
      float4 av = *reinterpret_cast<const float4*>(&As[kk][ty << 2]);
      float4 bv = *reinterpret_cast<const float4*>(&Bs[kk][tx << 2]);
      float a_[4] = {av.x, av.y, av.z, av.w};
      float b_[4] = {bv.x, bv.y, bv.z, bv.w};
#pragma unroll
      for (int i = 0; i < 4; i++)
#pragma unroll
        for (int j = 0; j < 4; j++)
          acc[i][j] = fmaf(a_[i], b_[j], acc[i][j]);
    }
    __syncthreads();
  }

#pragma unroll
  for (int i = 0; i < 4; i++) {
    int m = m0 + (ty << 2) + i;
    float4 o;
    o.x = acc[i][0]; o.y = acc[i][1]; o.z = acc[i][2]; o.w = acc[i][3];
    if (BIAS) {
      float4 bb = *reinterpret_cast<const float4*>(&bias[n0 + (tx << 2)]);
      o.x += bb.x; o.y += bb.y; o.z += bb.z; o.w += bb.w;
    }
    if (RELU) {
      o.x = fmaxf(o.x, 0.f); o.y = fmaxf(o.y, 0.f);
      o.z = fmaxf(o.z, 0.f); o.w = fmaxf(o.w, 0.f);
    }
    *reinterpret_cast<float4*>(&C[(size_t)m * Dn + n0 + (tx << 2)]) = o;
  }
}

// ---------------------------------------------------------------------------
// MFMA attention. Block = 64 q-rows (4 waves x 16), one (b,h).
// Swapped QK^T: S^T = mfma(K_tile, Q^T)  -> lane holds full score row of its
// q-row (col = lane&15) across 4 kgroups; softmax = regs + 2 shfl_xor.
// K staged bf16 [128][64] XOR-swizzled; V staged transposed [64][s:136] bf16.
// P per-wave LDS [16][136] bf16. fp32 in, fp32 out.
// ---------------------------------------------------------------------------
__global__ __launch_bounds__(256) void attn_k(
    const float* __restrict__ q, const float* __restrict__ kx,
    const float* __restrict__ vx, float* __restrict__ o)
{
  __shared__ __align__(16) unsigned char KVl[17408];  // K: [128][128B] swz / V^T: [64][272B]
  __shared__ __align__(16) unsigned char Pl[4 * 4352];  // per-wave P [16][272B]

  const int blkq = blockIdx.x;   // 0..7 (64-row q chunk)
  const int h    = blockIdx.y;
  const int b    = blockIdx.z;
  const int tid  = threadIdx.x;
  const int lane = tid & 63;
  const int wv   = tid >> 6;
  const int qcol = lane & 15;
  const int g    = lane >> 4;

  const size_t kvbase = (size_t)(b * Tn) * Dn + h * DKn;
  const size_t qrow0  = (size_t)(b * Tn + blkq * 64 + wv * 16);

  // Q fragments (this wave's 16 rows), loaded once from global fp32.
  bf16x8 qf[2];
  {
    const float* qp = &q[(qrow0 + qcol) * Dn + h * DKn + g * 8];
#pragma unroll
    for (int ks = 0; ks < 2; ks++) {
      float4 a = *reinterpret_cast<const float4*>(qp + ks * 32);
      float4 c = *reinterpret_cast<const float4*>(qp + ks * 32 + 4);
      qf[ks] = cvt8(a, c);
    }
  }

  f32x4 sf[32];
#pragma unroll
  for (int t = 0; t < 32; t++) sf[t] = (f32x4){0.f, 0.f, 0.f, 0.f};

  // ---- Phase 1: S^T = K @ Q^T over 4 chunks of 128 s-rows ----
  for (int c = 0; c < 4; c++) {
#pragma unroll
    for (int i = 0; i < 4; i++) {
      int idx = (i << 8) + tid;
      int row = idx >> 3;
      int c16 = idx & 7;
      const float* src = &kx[kvbase + (size_t)(c * 128 + row) * Dn + c16 * 8];
      float4 v0 = *reinterpret_cast<const float4*>(src);
      float4 v1 = *reinterpret_cast<const float4*>(src + 4);
      uint4 w;
      w.x = pack2bf(v0.x, v0.y); w.y = pack2bf(v0.z, v0.w);
      w.z = pack2bf(v1.x, v1.y); w.w = pack2bf(v1.z, v1.w);
      *reinterpret_cast<uint4*>(&KVl[row * 128 + ((c16 * 16) ^ ((row & 7) << 4))]) = w;
    }
    __syncthreads();
#pragma unroll
    for (int t = 0; t < 8; t++) {
      const int srow = t * 16 + qcol;
      const int rb = srow * 128;
      const int sw = (srow & 7) << 4;
#pragma unroll
      for (int ks = 0; ks < 2; ks++) {
        bf16x8 a = *reinterpret_cast<const bf16x8*>(&KVl[rb + ((ks * 64 + g * 16) ^ sw)]);
        sf[c * 8 + t] = __builtin_amdgcn_mfma_f32_16x16x32_bf16(a, qf[ks], sf[c * 8 + t], 0, 0, 0);
      }
    }
    __syncthreads();
  }

  // ---- Phase 2: softmax, fully in registers (row = this lane's qcol) ----
  float mx = -3e38f;
#pragma unroll
  for (int t = 0; t < 32; t++)
#pragma unroll
    for (int r = 0; r < 4; r++) {
      float s = sf[t][r] * 0.125f;
      sf[t][r] = s;
      mx = fmaxf(mx, s);
    }
  mx = fmaxf(mx, __shfl_xor(mx, 16, 64));
  mx = fmaxf(mx, __shfl_xor(mx, 32, 64));
  float sum = 0.f;
#pragma unroll
  for (int t = 0; t < 32; t++)
#pragma unroll
    for (int r = 0; r < 4; r++) {
      float e = __expf(sf[t][r] - mx);
      sf[t][r] = e;
      sum += e;
    }
  sum += __shfl_xor(sum, 16, 64);
  sum += __shfl_xor(sum, 32, 64);
  const float inv = 1.f / sum;

  // ---- Phase 3: O = P @ V over 4 chunks ----
  f32x4 oa[4];
#pragma unroll
  for (int nt = 0; nt < 4; nt++) oa[nt] = (f32x4){0.f, 0.f, 0.f, 0.f};

  unsigned char* Pw = &Pl[wv * 4352];

  for (int c = 0; c < 4; c++) {
    // stage V^T (bf16): Vt[dk][s], stride 272B
#pragma unroll
    for (int i = 0; i < 4; i++) {
      int idx = (i << 8) + tid;
      int sL  = idx & 127;
      int dk8 = (idx >> 7) << 3;
      const float* src = &vx[kvbase + (size_t)(c * 128 + sL) * Dn + dk8];
      float4 v0 = *reinterpret_cast<const float4*>(src);
      float4 v1 = *reinterpret_cast<const float4*>(src + 4);
      float vals[8] = {v0.x, v0.y, v0.z, v0.w, v1.x, v1.y, v1.z, v1.w};
#pragma unroll
      for (int j = 0; j < 8; j++)
        *reinterpret_cast<unsigned short*>(&KVl[(dk8 + j) * 272 + sL * 2]) = f2bf(vals[j]);
    }
    // write this wave's P chunk [16 q][128 s] bf16, stride 272B
#pragma unroll
    for (int t8 = 0; t8 < 8; t8++) {
      const int t = c * 8 + t8;
#pragma unroll
      for (int rp = 0; rp < 2; rp++) {
        unsigned int pw = pack2bf(sf[t][2 * rp] * inv, sf[t][2 * rp + 1] * inv);
        *reinterpret_cast<unsigned int*>(
            &Pw[qcol * 272 + (t8 * 16 + g * 4 + rp * 2) * 2]) = pw;
      }
    }
    __syncthreads();

    bf16x8 pa[4];
#pragma unroll
    for (int ks = 0; ks < 4; ks++)
      pa[ks] = *reinterpret_cast<const bf16x8*>(&Pw[qcol * 272 + ks * 64 + g * 16]);
#pragma unroll
    for (int nt = 0; nt < 4; nt++) {
#pragma unroll
      for (int ks = 0; ks < 4; ks++) {
        bf16x8 bvf = *reinterpret_cast<const bf16x8*>(
            &KVl[(nt * 16 + qcol) * 272 + ks * 64 + g * 16]);
        oa[nt] = __builtin_amdgcn_mfma_f32_16x16x32_bf16(pa[ks], bvf, oa[nt], 0, 0, 0);
      }
    }
    __syncthreads();
  }

  // ---- Output: O C-frag row = 4g+r, col = qcol (+16*nt) ----
  const size_t obase = qrow0 * Dn + h * DKn;
#pragma unroll
  for (int nt = 0; nt < 4; nt++)
#pragma unroll
    for (int r = 0; r < 4; r++)
      o[obase + (size_t)(4 * g + r) * Dn + nt * 16 + qcol] = oa[nt][r];
}

// ---------------------------------------------------------------------------
// r = a + b (elementwise), plus per-block partial column sums / sumsq.
// ---------------------------------------------------------------------------
__global__ __launch_bounds__(256) void add_stats_k(
    const float* __restrict__ a, const float* __restrict__ b,
    float* __restrict__ r, float* __restrict__ ps, float* __restrict__ pq)
{
  const int blk = blockIdx.x;
  const int tid = threadIdx.x;
  const int c4 = tid << 2;
  const int row0 = blk << 4;
  float s0 = 0, s1 = 0, s2 = 0, s3 = 0;
  float q0 = 0, q1 = 0, q2 = 0, q3 = 0;
#pragma unroll 4
  for (int i = 0; i < 16; i++) {
    size_t off = (size_t)(row0 + i) * Dn + c4;
    float4 av = *reinterpret_cast<const float4*>(&a[off]);
    float4 bv = *reinterpret_cast<const float4*>(&b[off]);
    float4 rv = make_float4(av.x + bv.x, av.y + bv.y, av.z + bv.z, av.w + bv.w);
    *reinterpret_cast<float4*>(&r[off]) = rv;
    s0 += rv.x; q0 = fmaf(rv.x, rv.x, q0);
    s1 += rv.y; q1 = fmaf(rv.y, rv.y, q1);
    s2 += rv.z; q2 = fmaf(rv.z, rv.z, q2);
    s3 += rv.w; q3 = fmaf(rv.w, rv.w, q3);
  }
  size_t po = (size_t)blk * Dn + c4;
  *reinterpret_cast<float4*>(&ps[po]) = make_float4(s0, s1, s2, s3);
  *reinterpret_cast<float4*>(&pq[po]) = make_float4(q0, q1, q2, q3);
}

__global__ __launch_bounds__(256) void reduce_stats_k(
    const float* __restrict__ ps, const float* __restrict__ pq,
    const float* __restrict__ g, const float* __restrict__ be,
    float* __restrict__ scale, float* __restrict__ shift)
{
  const int col = blockIdx.x * 256 + threadIdx.x;
  float s = 0.f, q = 0.f;
  for (int p = 0; p < 256; p++) {
    s += ps[(size_t)p * Dn + col];
    q += pq[(size_t)p * Dn + col];
  }
  const float invn = 1.f / 4096.f;
  float mean = s * invn;
  float var = q * invn - mean * mean;
  float inv = rsqrtf(var + 1e-3f);
  float sc = g[col] * inv;
  scale[col] = sc;
  shift[col] = be[col] - mean * sc;
}

__global__ __launch_bounds__(256) void norm_k(
    const float* __restrict__ r, const float* __restrict__ scale,
    const float* __restrict__ shift, float* __restrict__ o)
{
  const int idx = blockIdx.x * 256 + threadIdx.x;
  const int c4 = (idx & 255) << 2;
  float4 rv = *reinterpret_cast<const float4*>(&r[(size_t)idx << 2]);
  float4 sc = *reinterpret_cast<const float4*>(&scale[c4]);
  float4 sh = *reinterpret_cast<const float4*>(&shift[c4]);
  float4 ov = make_float4(fmaf(rv.x, sc.x, sh.x), fmaf(rv.y, sc.y, sh.y),
                          fmaf(rv.z, sc.z, sh.z), fmaf(rv.w, sc.w, sh.w));
  *reinterpret_cast<float4*>(&o[(size_t)idx << 2]) = ov;
}

// ---------------------------------------------------------------------------
extern "C" void kernel_launch(void* const* d_in, const int* in_sizes, int n_in,
                              void* d_out, int out_size, void* d_ws, size_t ws_size,
                              hipStream_t stream)
{
  const float* x   = (const float*)d_in[0];
  const float* wq  = (const float*)d_in[1];
  const float* wk  = (const float*)d_in[2];
  const float* wv  = (const float*)d_in[3];
  const float* W   = (const float*)d_in[4];
  const float* W1  = (const float*)d_in[5];
  const float* b1  = (const float*)d_in[6];
  const float* W2  = (const float*)d_in[7];
  const float* b2  = (const float*)d_in[8];
  const float* g1  = (const float*)d_in[9];
  const float* be1 = (const float*)d_in[10];
  const float* g2  = (const float*)d_in[11];
  const float* be2 = (const float*)d_in[12];

  float* out = (float*)d_out;
  float* ws  = (float*)d_ws;

  const size_t NB = (size_t)Mn * Dn;
  float* ws0 = ws;
  float* ws1 = ws + NB;
  float* ws2 = ws + 2 * NB;
  float* psum   = ws + 3 * NB;
  float* psumsq = psum + 256 * Dn;
  float* scale  = psumsq + 256 * Dn;
  float* shift  = scale + Dn;

  dim3 blk(256);
  dim3 gemm_grid(Dn / 64, Mn / 64, 1);
  dim3 qkv_grid(Dn / 64, Mn / 64, 3);

  // 1. q,k,v projections -> ws0, ws1, ws2
  gemm_k<1, 0, 0><<<qkv_grid, blk, 0, stream>>>(x, wq, wk, wv, nullptr,
                                                ws0, ws1, ws2, Dn, Dn);
  // 2. attention concat -> d_out (scratch)
  attn_k<<<dim3(Tn / 64, Hn, Bn), blk, 0, stream>>>(ws0, ws1, ws2, out);
  // 3. out = concat @ W -> ws0
  gemm_k<0, 0, 0><<<gemm_grid, blk, 0, stream>>>(out, W, nullptr, nullptr, nullptr,
                                                 ws0, nullptr, nullptr, Dn, Dn);
  // 4. r1 = x + out -> ws1 (+ stats)
  add_stats_k<<<dim3(Mn / 16), blk, 0, stream>>>(x, ws0, ws1, psum, psumsq);
  reduce_stats_k<<<dim3(4), blk, 0, stream>>>(psum, psumsq, g1, be1, scale, shift);
  // 5. out1 -> ws2
  norm_k<<<dim3(NB / 1024), blk, 0, stream>>>(ws1, scale, shift, ws2);
  // 6. h = relu(out1 @ W1 + b1) -> d_out (scratch)
  gemm_k<0, 1, 1><<<gemm_grid, blk, 0, stream>>>(ws2, W1, nullptr, nullptr, b1,
                                                 out, nullptr, nullptr, Dn, Dn);
  // 7. out2 = h @ W2 + b2 -> ws0
  gemm_k<0, 1, 0><<<gemm_grid, blk, 0, stream>>>(out, W2, nullptr, nullptr, b2,
                                                 ws0, nullptr, nullptr, Dn, Dn);
  // 8. r2 = out1 + out2 -> ws1 (+ stats)
  add_stats_k<<<dim3(Mn / 16), blk, 0, stream>>>(ws2, ws0, ws1, psum, psumsq);
  reduce_stats_k<<<dim3(4), blk, 0, stream>>>(psum, psumsq, g2, be2, scale, shift);
  // 9. final BN -> d_out
  norm_k<<<dim3(NB / 1024), blk, 0, stream>>>(ws1, scale, shift, out);
}

// Round 3
// 261.531 us; speedup vs baseline: 6.7105x; 3.2440x over previous
//
#include <hip/hip_runtime.h>
#include <hip/hip_bf16.h>
#include <cstdint>

#define Bn 8
#define Tn 512
#define Dn 1024
#define Hn 16
#define DKn 64
#define Mn (Bn * Tn)   // 4096

typedef unsigned short u16;
typedef short bf16x8 __attribute__((ext_vector_type(8)));
typedef float f32x4 __attribute__((ext_vector_type(4)));

__device__ __forceinline__ u16 f2bf(float f) {
  unsigned int u = __builtin_bit_cast(unsigned int, f);
  u += 0x7fffu + ((u >> 16) & 1u);
  return (u16)(u >> 16);
}
__device__ __forceinline__ unsigned int pack2bf(float lo, float hi) {
  return (unsigned int)f2bf(lo) | ((unsigned int)f2bf(hi) << 16);
}

// async global->LDS, 16B per lane; lds ptr must be wave-uniform.
__device__ __forceinline__ void gl2lds16(const void* g, void* l) {
  __builtin_amdgcn_global_load_lds(
      (const __attribute__((address_space(1))) unsigned int*)g,
      (__attribute__((address_space(3))) unsigned int*)l,
      16, 0, 0);
}

// ---------------------------------------------------------------------------
// fp32 -> bf16 elementwise (8 elems/thread)
// ---------------------------------------------------------------------------
__global__ __launch_bounds__(256) void cvt_bf16_k(
    const float* __restrict__ src, u16* __restrict__ dst)
{
  const size_t i = ((size_t)blockIdx.x * 256 + threadIdx.x) * 8;
  float4 a = *reinterpret_cast<const float4*>(&src[i]);
  float4 b = *reinterpret_cast<const float4*>(&src[i + 4]);
  uint4 w;
  w.x = pack2bf(a.x, a.y); w.y = pack2bf(a.z, a.w);
  w.z = pack2bf(b.x, b.y); w.w = pack2bf(b.z, b.w);
  *reinterpret_cast<uint4*>(&dst[i]) = w;
}

// ---------------------------------------------------------------------------
// Transpose+convert QKV weights (H,D,DK) fp32 -> WqkvT[3072][1024] bf16.
// Coalesced reads (lane = dk col), 32B row-chunk writes.
// ---------------------------------------------------------------------------
__global__ __launch_bounds__(256) void tqkv_k(
    const float* __restrict__ wq, const float* __restrict__ wk,
    const float* __restrict__ wv, u16* __restrict__ dst)
{
  const int kt = blockIdx.x;            // 0..15 k-tile of 64
  const int y  = blockIdx.y;            // 0..47
  const int tau = y >> 4, head = y & 15;
  const float* src = (tau == 0 ? wq : tau == 1 ? wk : wv) + (size_t)head * 65536;
  const int t = threadIdx.x;
  const int n  = t & 63;                // dk
  const int kq = (t >> 6) << 4;         // 0,16,32,48
  const int k0 = kt << 6;
  u16 v[16];
#pragma unroll
  for (int j = 0; j < 16; j++)
    v[j] = f2bf(src[(size_t)(k0 + kq + j) * 64 + n]);
  u16* d = &dst[((size_t)tau * 1024 + head * 64 + n) * 1024 + k0 + kq];
  *reinterpret_cast<uint4*>(&d[0]) = *reinterpret_cast<uint4*>(&v[0]);
  *reinterpret_cast<uint4*>(&d[8]) = *reinterpret_cast<uint4*>(&v[8]);
}

// W/W1/W2 [1024][1024] fp32 -> [N][K] bf16 transposed
__global__ __launch_bounds__(256) void tw_k(
    const float* __restrict__ W, const float* __restrict__ W1,
    const float* __restrict__ W2, u16* __restrict__ wt,
    u16* __restrict__ w1t, u16* __restrict__ w2t)
{
  const int kt = blockIdx.x, ntl = blockIdx.y, z = blockIdx.z;
  const float* src = (z == 0 ? W : z == 1 ? W1 : W2);
  u16* dst = (z == 0 ? wt : z == 1 ? w1t : w2t);
  const int t = threadIdx.x;
  const int n  = (ntl << 6) + (t & 63);
  const int kq = (t >> 6) << 4;
  const int k0 = kt << 6;
  u16 v[16];
#pragma unroll
  for (int j = 0; j < 16; j++)
    v[j] = f2bf(src[(size_t)(k0 + kq + j) * 1024 + n]);
  u16* d = &dst[(size_t)n * 1024 + k0 + kq];
  *reinterpret_cast<uint4*>(&d[0]) = *reinterpret_cast<uint4*>(&v[0]);
  *reinterpret_cast<uint4*>(&d[8]) = *reinterpret_cast<uint4*>(&v[8]);
}

// ---------------------------------------------------------------------------
// bf16 MFMA GEMM: C[M,N] = A[M,K=1024] @ Bt[N,K]^T. Tile 128x128, BK=32,
// 8 waves (wave tile 64x32). global_load_lds staging with XOR-swizzled
// source + swizzled ds_read_b128 fragment reads (rule 21).
// ---------------------------------------------------------------------------
template<int BIAS, int RELU, int OUTBF>
__global__ __launch_bounds__(512) void mgemm_k(
    const u16* __restrict__ A, const u16* __restrict__ Bt,
    const float* __restrict__ bias,
    float* __restrict__ Cf, u16* __restrict__ Cb, int ldc)
{
  __shared__ __align__(16) u16 As[4096];   // [128 rows][32 k] bf16, swizzled
  __shared__ __align__(16) u16 Bs[4096];

  const int tid  = threadIdx.x;
  const int lane = tid & 63;
  const int wid  = tid >> 6;
  const int wm = wid >> 2, wn = wid & 3;
  const int g4 = lane >> 4, r15 = lane & 15;
  const int m0 = blockIdx.y << 7, n0 = blockIdx.x << 7;

  // staging: one issue covers the whole 128x32 tile (512 lanes x 16B)
  const int srow  = tid >> 2;            // 0..127
  const int sslot = tid & 3;
  const int ssw   = (srow ^ (srow >> 2)) & 3;
  const int sk8   = ((sslot ^ ssw) << 3);          // element offset in k
  const u16* ga0 = &A[(size_t)(m0 + srow) * 1024 + sk8];
  const u16* gb0 = &Bt[(size_t)(n0 + srow) * 1024 + sk8];
  char* lA = (char*)As + wid * 1024;     // wave-uniform LDS base
  char* lB = (char*)Bs + wid * 1024;

  f32x4 acc[4][2] = {};

  for (int k0 = 0; k0 < 1024; k0 += 32) {
    gl2lds16(ga0 + k0, lA);
    gl2lds16(gb0 + k0, lB);
    __syncthreads();

    bf16x8 af[4], bfr[2];
#pragma unroll
    for (int m = 0; m < 4; m++) {
      int row = wm * 64 + m * 16 + r15;
      int sw = (row ^ (row >> 2)) & 3;
      af[m] = *reinterpret_cast<const bf16x8*>(
          (const char*)As + row * 64 + ((g4 ^ sw) << 4));
    }
#pragma unroll
    for (int n = 0; n < 2; n++) {
      int row = wn * 32 + n * 16 + r15;
      int sw = (row ^ (row >> 2)) & 3;
      bfr[n] = *reinterpret_cast<const bf16x8*>(
          (const char*)Bs + row * 64 + ((g4 ^ sw) << 4));
    }
#pragma unroll
    for (int m = 0; m < 4; m++)
#pragma unroll
      for (int n = 0; n < 2; n++)
        acc[m][n] = __builtin_amdgcn_mfma_f32_16x16x32_bf16(af[m], bfr[n], acc[m][n], 0, 0, 0);
    __syncthreads();
  }

  float bb[2] = {0.f, 0.f};
  if (BIAS) {
#pragma unroll
    for (int n = 0; n < 2; n++) bb[n] = bias[n0 + wn * 32 + n * 16 + r15];
  }
#pragma unroll
  for (int m = 0; m < 4; m++) {
    int row = m0 + wm * 64 + m * 16 + g4 * 4;
#pragma unroll
    for (int n = 0; n < 2; n++) {
      int col = n0 + wn * 32 + n * 16 + r15;
#pragma unroll
      for (int j = 0; j < 4; j++) {
        float v = acc[m][n][j];
        if (BIAS) v += bb[n];
        if (RELU) v = fmaxf(v, 0.f);
        if (OUTBF) Cb[(size_t)(row + j) * ldc + col] = f2bf(v);
        else       Cf[(size_t)(row + j) * ldc + col] = v;
      }
    }
  }
}

// ---------------------------------------------------------------------------
// MFMA attention on bf16 qkv (combined [4096][3072]: q|k|v).
// Block = 64 q-rows (4 waves x 16), one (b,h). Swapped QK^T, in-reg softmax.
// K staged via global_load_lds with pre-swizzled source; V^T reg-staged.
// Output: bf16 concat [4096][1024].
// ---------------------------------------------------------------------------
__global__ __launch_bounds__(256) void attn_k(
    const u16* __restrict__ qkv, u16* __restrict__ o)
{
  __shared__ __align__(16) unsigned char KVl[17408];  // K[128][128B] swz / V^T[64][272B]
  __shared__ __align__(16) unsigned char Pl[4 * 4352];

  const int blkq = blockIdx.x;
  const int h    = blockIdx.y;
  const int b    = blockIdx.z;
  const int tid  = threadIdx.x;
  const int lane = tid & 63;
  const int wv   = tid >> 6;
  const int qcol = lane & 15;
  const int g    = lane >> 4;
  const int QS   = 3072;

  const size_t rowbase = (size_t)(b * Tn);
  const size_t qrow0   = rowbase + blkq * 64 + wv * 16;

  // Q fragments (this wave's 16 rows)
  bf16x8 qf[2];
  {
    const u16* qp = &qkv[(qrow0 + qcol) * QS + h * DKn + g * 8];
    qf[0] = *reinterpret_cast<const bf16x8*>(qp);
    qf[1] = *reinterpret_cast<const bf16x8*>(qp + 32);
  }

  f32x4 sf[32];
#pragma unroll
  for (int t = 0; t < 32; t++) sf[t] = (f32x4){0.f, 0.f, 0.f, 0.f};

  // K staging constants (global_load_lds, swizzled source)
  const int r8 = tid >> 3;                          // wv*8 + lane>>3
  const int sk = (((tid & 7) ^ (r8 & 7)) << 3);     // element offset in dk
  char* lK = (char*)KVl + wv * 1024;

  // ---- Phase 1: S^T = K @ Q^T over 4 chunks of 128 s-rows ----
  for (int c = 0; c < 4; c++) {
#pragma unroll
    for (int i = 0; i < 4; i++) {
      const u16* gk = &qkv[(rowbase + c * 128 + i * 32 + r8) * QS + 1024 + h * DKn + sk];
      gl2lds16(gk, lK + i * 4096);
    }
    __syncthreads();
#pragma unroll
    for (int t = 0; t < 8; t++) {
      const int srow = t * 16 + qcol;
      const int rb = srow * 128;
      const int sw = (srow & 7) << 4;
#pragma unroll
      for (int ks = 0; ks < 2; ks++) {
        bf16x8 a = *reinterpret_cast<const bf16x8*>(&KVl[rb + ((ks * 64 + g * 16) ^ sw)]);
        sf[c * 8 + t] = __builtin_amdgcn_mfma_f32_16x16x32_bf16(a, qf[ks], sf[c * 8 + t], 0, 0, 0);
      }
    }
    __syncthreads();
  }

  // ---- Phase 2: softmax in registers ----
  float mx = -3e38f;
#pragma unroll
  for (int t = 0; t < 32; t++)
#pragma unroll
    for (int r = 0; r < 4; r++) {
      float s = sf[t][r] * 0.125f;
      sf[t][r] = s;
      mx = fmaxf(mx, s);
    }
  mx = fmaxf(mx, __shfl_xor(mx, 16, 64));
  mx = fmaxf(mx, __shfl_xor(mx, 32, 64));
  float sum = 0.f;
#pragma unroll
  for (int t = 0; t < 32; t++)
#pragma unroll
    for (int r = 0; r < 4; r++) {
      float e = __expf(sf[t][r] - mx);
      sf[t][r] = e;
      sum += e;
    }
  sum += __shfl_xor(sum, 16, 64);
  sum += __shfl_xor(sum, 32, 64);
  const float inv = 1.f / sum;

  // ---- Phase 3: O = P @ V over 4 chunks ----
  f32x4 oa[4];
#pragma unroll
  for (int nt = 0; nt < 4; nt++) oa[nt] = (f32x4){0.f, 0.f, 0.f, 0.f};

  unsigned char* Pw = &Pl[wv * 4352];

  for (int c = 0; c < 4; c++) {
    // stage V^T bf16: Vt[dk][s], stride 272B
#pragma unroll
    for (int i = 0; i < 4; i++) {
      int idx = (i << 8) + tid;
      int sL  = idx & 127;
      int dk8 = (idx >> 7) << 3;
      const u16* src = &qkv[(rowbase + c * 128 + sL) * QS + 2048 + h * DKn + dk8];
      union { uint4 u; u16 s[8]; } uu;
      uu.u = *reinterpret_cast<const uint4*>(src);
#pragma unroll
      for (int j = 0; j < 8; j++)
        *reinterpret_cast<u16*>(&KVl[(dk8 + j) * 272 + sL * 2]) = uu.s[j];
    }
    // write this wave's P chunk [16 q][128 s] bf16
#pragma unroll
    for (int t8 = 0; t8 < 8; t8++) {
      const int t = c * 8 + t8;
#pragma unroll
      for (int rp = 0; rp < 2; rp++) {
        unsigned int pw = pack2bf(sf[t][2 * rp] * inv, sf[t][2 * rp + 1] * inv);
        *reinterpret_cast<unsigned int*>(
            &Pw[qcol * 272 + (t8 * 16 + g * 4 + rp * 2) * 2]) = pw;
      }
    }
    __syncthreads();

    bf16x8 pa[4];
#pragma unroll
    for (int ks = 0; ks < 4; ks++)
      pa[ks] = *reinterpret_cast<const bf16x8*>(&Pw[qcol * 272 + ks * 64 + g * 16]);
#pragma unroll
    for (int nt = 0; nt < 4; nt++) {
#pragma unroll
      for (int ks = 0; ks < 4; ks++) {
        bf16x8 bvf = *reinterpret_cast<const bf16x8*>(
            &KVl[(nt * 16 + qcol) * 272 + ks * 64 + g * 16]);
        oa[nt] = __builtin_amdgcn_mfma_f32_16x16x32_bf16(pa[ks], bvf, oa[nt], 0, 0, 0);
      }
    }
    __syncthreads();
  }

  // ---- Output: bf16 concat ----
#pragma unroll
  for (int nt = 0; nt < 4; nt++)
#pragma unroll
    for (int r = 0; r < 4; r++)
      o[(qrow0 + 4 * g + r) * 1024 + h * DKn + nt * 16 + qcol] = f2bf(oa[nt][r]);
}

// ---------------------------------------------------------------------------
// r = a + b, plus per-block partial column sums / sumsq.
// ---------------------------------------------------------------------------
__global__ __launch_bounds__(256) void add_stats_k(
    const float* __restrict__ a, const float* __restrict__ b,
    float* __restrict__ r, float* __restrict__ ps, float* __restrict__ pq)
{
  const int blk = blockIdx.x;
  const int tid = threadIdx.x;
  const int c4 = tid << 2;
  const int row0 = blk << 4;
  float s0 = 0, s1 = 0, s2 = 0, s3 = 0;
  float q0 = 0, q1 = 0, q2 = 0, q3 = 0;
#pragma unroll 4
  for (int i = 0; i < 16; i++) {
    size_t off = (size_t)(row0 + i) * Dn + c4;
    float4 av = *reinterpret_cast<const float4*>(&a[off]);
    float4 bv = *reinterpret_cast<const float4*>(&b[off]);
    float4 rv = make_float4(av.x + bv.x, av.y + bv.y, av.z + bv.z, av.w + bv.w);
    *reinterpret_cast<float4*>(&r[off]) = rv;
    s0 += rv.x; q0 = fmaf(rv.x, rv.x, q0);
    s1 += rv.y; q1 = fmaf(rv.y, rv.y, q1);
    s2 += rv.z; q2 = fmaf(rv.z, rv.z, q2);
    s3 += rv.w; q3 = fmaf(rv.w, rv.w, q3);
  }
  size_t po = (size_t)blk * Dn + c4;
  *reinterpret_cast<float4*>(&ps[po]) = make_float4(s0, s1, s2, s3);
  *reinterpret_cast<float4*>(&pq[po]) = make_float4(q0, q1, q2, q3);
}

__global__ __launch_bounds__(256) void reduce_stats_k(
    const float* __restrict__ ps, const float* __restrict__ pq,
    const float* __restrict__ g, const float* __restrict__ be,
    float* __restrict__ scale, float* __restrict__ shift)
{
  const int col = blockIdx.x * 256 + threadIdx.x;
  float s = 0.f, q = 0.f;
  for (int p = 0; p < 256; p++) {
    s += ps[(size_t)p * Dn + col];
    q += pq[(size_t)p * Dn + col];
  }
  const float invn = 1.f / 4096.f;
  float mean = s * invn;
  float var = q * invn - mean * mean;
  float inv = rsqrtf(var + 1e-3f);
  float sc = g[col] * inv;
  scale[col] = sc;
  shift[col] = be[col] - mean * sc;
}

template<int DUAL>
__global__ __launch_bounds__(256) void norm_k(
    const float* __restrict__ r, const float* __restrict__ scale,
    const float* __restrict__ shift, float* __restrict__ o, u16* __restrict__ ob)
{
  const size_t idx = (size_t)blockIdx.x * 256 + threadIdx.x;   // float4 index
  const int c4 = ((int)idx & 255) << 2;
  float4 rv = *reinterpret_cast<const float4*>(&r[idx << 2]);
  float4 sc = *reinterpret_cast<const float4*>(&scale[c4]);
  float4 sh = *reinterpret_cast<const float4*>(&shift[c4]);
  float4 ov = make_float4(fmaf(rv.x, sc.x, sh.x), fmaf(rv.y, sc.y, sh.y),
                          fmaf(rv.z, sc.z, sh.z), fmaf(rv.w, sc.w, sh.w));
  *reinterpret_cast<float4*>(&o[idx << 2]) = ov;
  if (DUAL) {
    uint2 p;
    p.x = pack2bf(ov.x, ov.y);
    p.y = pack2bf(ov.z, ov.w);
    *reinterpret_cast<uint2*>(&ob[idx << 2]) = p;
  }
}

// ---------------------------------------------------------------------------
extern "C" void kernel_launch(void* const* d_in, const int* in_sizes, int n_in,
                              void* d_out, int out_size, void* d_ws, size_t ws_size,
                              hipStream_t stream)
{
  const float* x   = (const float*)d_in[0];
  const float* wq  = (const float*)d_in[1];
  const float* wk  = (const float*)d_in[2];
  const float* wv  = (const float*)d_in[3];
  const float* W   = (const float*)d_in[4];
  const float* W1  = (const float*)d_in[5];
  const float* b1  = (const float*)d_in[6];
  const float* W2  = (const float*)d_in[7];
  const float* b2  = (const float*)d_in[8];
  const float* g1  = (const float*)d_in[9];
  const float* be1 = (const float*)d_in[10];
  const float* g2  = (const float*)d_in[11];
  const float* be2 = (const float*)d_in[12];

  float* out = (float*)d_out;
  float* ws  = (float*)d_ws;

  const size_t NB = (size_t)Mn * Dn;   // 4M
  float* ws1    = ws;                  // residual sums (fp32)
  float* ws2    = ws1 + NB;            // out1 (fp32)
  float* psum   = ws2 + NB;            // 256*1024
  float* psumsq = psum + 256 * Dn;
  float* scale  = psumsq + 256 * Dn;
  float* shift  = scale + Dn;
  u16* xb      = (u16*)(shift + Dn);   // 4M bf16
  u16* qkvb    = xb + NB;              // 12M bf16
  u16* concatb = qkvb + 3 * NB;        // 4M bf16
  u16* wqkvT   = concatb + NB;         // 3M bf16
  u16* wt      = wqkvT + 3 * 1048576;  // 1M each
  u16* w1t     = wt + 1048576;
  u16* w2t     = w1t + 1048576;
  // aliases (qkvb dead after attn):
  u16* out1b = qkvb;
  u16* hb    = qkvb + NB;

  dim3 b256(256), b512(512);

  // 0. converts / transposes
  cvt_bf16_k<<<dim3(2048), b256, 0, stream>>>(x, xb);
  tqkv_k<<<dim3(16, 48), b256, 0, stream>>>(wq, wk, wv, wqkvT);
  tw_k<<<dim3(16, 16, 3), b256, 0, stream>>>(W, W1, W2, wt, w1t, w2t);

  // 1. qkv = x @ [Wq|Wk|Wv]  (bf16 out, ldc 3072)
  mgemm_k<0, 0, 1><<<dim3(24, 32), b512, 0, stream>>>(xb, wqkvT, nullptr,
                                                      nullptr, qkvb, 3072);
  // 2. attention -> concat bf16
  attn_k<<<dim3(Tn / 64, Hn, Bn), b256, 0, stream>>>(qkvb, concatb);
  // 3. out = concat @ W -> fp32 (d_out as scratch)
  mgemm_k<0, 0, 0><<<dim3(8, 32), b512, 0, stream>>>(concatb, wt, nullptr,
                                                     out, nullptr, 1024);
  // 4. r1 = x + out -> ws1 (+stats)
  add_stats_k<<<dim3(Mn / 16), b256, 0, stream>>>(x, out, ws1, psum, psumsq);
  reduce_stats_k<<<dim3(4), b256, 0, stream>>>(psum, psumsq, g1, be1, scale, shift);
  // 5. out1 -> ws2 (fp32) + out1b (bf16)
  norm_k<1><<<dim3(NB / 1024), b256, 0, stream>>>(ws1, scale, shift, ws2, out1b);
  // 6. h = relu(out1 @ W1 + b1) -> bf16
  mgemm_k<1, 1, 1><<<dim3(8, 32), b512, 0, stream>>>(out1b, w1t, b1,
                                                     nullptr, hb, 1024);
  // 7. out2 = h @ W2 + b2 -> fp32 (d_out as scratch)
  mgemm_k<1, 0, 0><<<dim3(8, 32), b512, 0, stream>>>(hb, w2t, b2,
                                                     out, nullptr, 1024);
  // 8. r2 = out1 + out2 -> ws1 (+stats)
  add_stats_k<<<dim3(Mn / 16), b256, 0, stream>>>(ws2, out, ws1, psum, psumsq);
  reduce_stats_k<<<dim3(4), b256, 0, stream>>>(psum, psumsq, g2, be2, scale, shift);
  // 9. final BN -> d_out
  norm_k<0><<<dim3(NB / 1024), b256, 0, stream>>>(ws1, scale, shift, out, nullptr);
}

// Round 4
// 185.433 us; speedup vs baseline: 9.4644x; 1.4104x over previous
//
#include <hip/hip_runtime.h>
#include <hip/hip_bf16.h>
#include <cstdint>

#define Bn 8
#define Tn 512
#define Dn 1024
#define Hn 16
#define DKn 64
#define Mn (Bn * Tn)   // 4096

typedef unsigned short u16;
typedef short bf16x8 __attribute__((ext_vector_type(8)));
typedef float f32x4 __attribute__((ext_vector_type(4)));

__device__ __forceinline__ u16 f2bf(float f) {
  unsigned int u = __builtin_bit_cast(unsigned int, f);
  u += 0x7fffu + ((u >> 16) & 1u);
  return (u16)(u >> 16);
}
__device__ __forceinline__ unsigned int pack2bf(float lo, float hi) {
  return (unsigned int)f2bf(lo) | ((unsigned int)f2bf(hi) << 16);
}

// async global->LDS, 16B per lane; lds ptr must be wave-uniform + lane*16.
__device__ __forceinline__ void gl2lds16(const void* g, void* l) {
  __builtin_amdgcn_global_load_lds(
      (const __attribute__((address_space(1))) unsigned int*)g,
      (__attribute__((address_space(3))) unsigned int*)l,
      16, 0, 0);
}

// ---------------------------------------------------------------------------
// fp32 -> bf16 elementwise
// ---------------------------------------------------------------------------
__global__ __launch_bounds__(256) void cvt_bf16_k(
    const float* __restrict__ src, u16* __restrict__ dst)
{
  const size_t i = ((size_t)blockIdx.x * 256 + threadIdx.x) * 8;
  float4 a = *reinterpret_cast<const float4*>(&src[i]);
  float4 b = *reinterpret_cast<const float4*>(&src[i + 4]);
  uint4 w;
  w.x = pack2bf(a.x, a.y); w.y = pack2bf(a.z, a.w);
  w.z = pack2bf(b.x, b.y); w.w = pack2bf(b.z, b.w);
  *reinterpret_cast<uint4*>(&dst[i]) = w;
}

// ---------------------------------------------------------------------------
// Transpose+convert QKV weights (H,D,DK) fp32 -> WqkvT[3072][1024] bf16.
// ---------------------------------------------------------------------------
__global__ __launch_bounds__(256) void tqkv_k(
    const float* __restrict__ wq, const float* __restrict__ wk,
    const float* __restrict__ wv, u16* __restrict__ dst)
{
  const int kt = blockIdx.x;
  const int y  = blockIdx.y;
  const int tau = y >> 4, head = y & 15;
  const float* src = (tau == 0 ? wq : tau == 1 ? wk : wv) + (size_t)head * 65536;
  const int t = threadIdx.x;
  const int n  = t & 63;
  const int kq = (t >> 6) << 4;
  const int k0 = kt << 6;
  u16 v[16];
#pragma unroll
  for (int j = 0; j < 16; j++)
    v[j] = f2bf(src[(size_t)(k0 + kq + j) * 64 + n]);
  u16* d = &dst[((size_t)tau * 1024 + head * 64 + n) * 1024 + k0 + kq];
  *reinterpret_cast<uint4*>(&d[0]) = *reinterpret_cast<uint4*>(&v[0]);
  *reinterpret_cast<uint4*>(&d[8]) = *reinterpret_cast<uint4*>(&v[8]);
}

// W/W1/W2 [1024][1024] fp32 -> [N][K] bf16 transposed
__global__ __launch_bounds__(256) void tw_k(
    const float* __restrict__ W, const float* __restrict__ W1,
    const float* __restrict__ W2, u16* __restrict__ wt,
    u16* __restrict__ w1t, u16* __restrict__ w2t)
{
  const int kt = blockIdx.x, ntl = blockIdx.y, z = blockIdx.z;
  const float* src = (z == 0 ? W : z == 1 ? W1 : W2);
  u16* dst = (z == 0 ? wt : z == 1 ? w1t : w2t);
  const int t = threadIdx.x;
  const int n  = (ntl << 6) + (t & 63);
  const int kq = (t >> 6) << 4;
  const int k0 = kt << 6;
  u16 v[16];
#pragma unroll
  for (int j = 0; j < 16; j++)
    v[j] = f2bf(src[(size_t)(k0 + kq + j) * 1024 + n]);
  u16* d = &dst[(size_t)n * 1024 + k0 + kq];
  *reinterpret_cast<uint4*>(&d[0]) = *reinterpret_cast<uint4*>(&v[0]);
  *reinterpret_cast<uint4*>(&d[8]) = *reinterpret_cast<uint4*>(&v[8]);
}

// ---------------------------------------------------------------------------
// bf16 MFMA GEMM: C[M,N] = A[M,1024] @ Bt[N,1024]^T. Tile 128x128, BK=32,
// 8 waves. OUTM: 0=fp32 C, 1=bf16 C, 2=no C.
// RES: r = acc(+bias) + Rres -> Rout (fp32) + per-(block,wm) partial col stats.
// VT: blocks x>=16 write V transposed into Vt[(b,h)][dk][512].
// ---------------------------------------------------------------------------
template<int BIAS, int RELU, int OUTM, int RES, int VT>
__global__ __launch_bounds__(512) void mgemm_k(
    const u16* __restrict__ A, const u16* __restrict__ Bt,
    const float* __restrict__ bias,
    float* __restrict__ Cf, u16* __restrict__ Cb, int ldc,
    const float* __restrict__ Rres, float* __restrict__ Rout,
    float* __restrict__ psum, float* __restrict__ psumsq,
    u16* __restrict__ Vt)
{
  __shared__ __align__(16) u16 As[4096];
  __shared__ __align__(16) u16 Bs[4096];

  const int tid  = threadIdx.x;
  const int lane = tid & 63;
  const int wid  = tid >> 6;
  const int wm = wid >> 2, wn = wid & 3;
  const int g4 = lane >> 4, r15 = lane & 15;
  const int m0 = blockIdx.y << 7, n0 = blockIdx.x << 7;

  const int srow  = tid >> 2;
  const int sslot = tid & 3;
  const int ssw   = (srow ^ (srow >> 2)) & 3;
  const int sk8   = ((sslot ^ ssw) << 3);
  const u16* ga0 = &A[(size_t)(m0 + srow) * 1024 + sk8];
  const u16* gb0 = &Bt[(size_t)(n0 + srow) * 1024 + sk8];
  char* lA = (char*)As + wid * 1024;
  char* lB = (char*)Bs + wid * 1024;

  f32x4 acc[4][2] = {};

  for (int k0 = 0; k0 < 1024; k0 += 32) {
    gl2lds16(ga0 + k0, lA);
    gl2lds16(gb0 + k0, lB);
    __syncthreads();

    bf16x8 af[4], bfr[2];
#pragma unroll
    for (int m = 0; m < 4; m++) {
      int row = wm * 64 + m * 16 + r15;
      int sw = (row ^ (row >> 2)) & 3;
      af[m] = *reinterpret_cast<const bf16x8*>(
          (const char*)As + row * 64 + ((g4 ^ sw) << 4));
    }
#pragma unroll
    for (int n = 0; n < 2; n++) {
      int row = wn * 32 + n * 16 + r15;
      int sw = (row ^ (row >> 2)) & 3;
      bfr[n] = *reinterpret_cast<const bf16x8*>(
          (const char*)Bs + row * 64 + ((g4 ^ sw) << 4));
    }
#pragma unroll
    for (int m = 0; m < 4; m++)
#pragma unroll
      for (int n = 0; n < 2; n++)
        acc[m][n] = __builtin_amdgcn_mfma_f32_16x16x32_bf16(af[m], bfr[n], acc[m][n], 0, 0, 0);
    __syncthreads();
  }

  // ---- VT epilogue: write V transposed ----
  if (VT && blockIdx.x >= 16) {
    const int vcol0 = n0 - 2048;
#pragma unroll
    for (int m = 0; m < 4; m++) {
      int row0 = m0 + wm * 64 + m * 16 + g4 * 4;
      int bI = row0 >> 9, s = row0 & 511;
#pragma unroll
      for (int n = 0; n < 2; n++) {
        int cv = vcol0 + wn * 32 + n * 16 + r15;
        int hh = cv >> 6, dk = cv & 63;
        uint2 pk;
        pk.x = pack2bf(acc[m][n][0], acc[m][n][1]);
        pk.y = pack2bf(acc[m][n][2], acc[m][n][3]);
        *reinterpret_cast<uint2*>(
            &Vt[(((size_t)(bI * 16 + hh) * 64 + dk) << 9) + s]) = pk;
      }
    }
    return;
  }

  float bb[2] = {0.f, 0.f};
  if (BIAS) {
#pragma unroll
    for (int n = 0; n < 2; n++) bb[n] = bias[n0 + wn * 32 + n * 16 + r15];
  }

  if (RES) {
    float sp[2] = {0.f, 0.f}, sq[2] = {0.f, 0.f};
#pragma unroll
    for (int m = 0; m < 4; m++) {
      int row = m0 + wm * 64 + m * 16 + g4 * 4;
#pragma unroll
      for (int n = 0; n < 2; n++) {
        int col = n0 + wn * 32 + n * 16 + r15;
#pragma unroll
        for (int j = 0; j < 4; j++) {
          float v = acc[m][n][j] + bb[n];
          float r = v + Rres[(size_t)(row + j) * 1024 + col];
          Rout[(size_t)(row + j) * 1024 + col] = r;
          sp[n] += r;
          sq[n] = fmaf(r, r, sq[n]);
        }
      }
    }
#pragma unroll
    for (int n = 0; n < 2; n++) {
      sp[n] += __shfl_xor(sp[n], 16, 64);
      sp[n] += __shfl_xor(sp[n], 32, 64);
      sq[n] += __shfl_xor(sq[n], 16, 64);
      sq[n] += __shfl_xor(sq[n], 32, 64);
    }
    if (g4 == 0) {
      int slot = (blockIdx.y << 1) + wm;
#pragma unroll
      for (int n = 0; n < 2; n++) {
        int col = n0 + wn * 32 + n * 16 + r15;
        psum[(size_t)slot * 1024 + col] = sp[n];
        psumsq[(size_t)slot * 1024 + col] = sq[n];
      }
    }
    return;
  }

#pragma unroll
  for (int m = 0; m < 4; m++) {
    int row = m0 + wm * 64 + m * 16 + g4 * 4;
#pragma unroll
    for (int n = 0; n < 2; n++) {
      int col = n0 + wn * 32 + n * 16 + r15;
#pragma unroll
      for (int j = 0; j < 4; j++) {
        float v = acc[m][n][j];
        if (BIAS) v += bb[n];
        if (RELU) v = fmaxf(v, 0.f);
        if (OUTM == 1)      Cb[(size_t)(row + j) * ldc + col] = f2bf(v);
        else if (OUTM == 0) Cf[(size_t)(row + j) * ldc + col] = v;
      }
    }
  }
}

// ---------------------------------------------------------------------------
// Flash MFMA attention. Grid (bh=128, qchunk=8); block = 64 q-rows (4 waves).
// qk: [4096][2048] bf16 (q | k per-head slabs). Vt: [(b,h)][64][512] bf16.
// Per 128-s chunk: stage K + V^T (global_load_lds, src-swizzled) -> QK^T ->
// online softmax (running m,l) -> P via swizzled per-wave LDS -> PV.
// ---------------------------------------------------------------------------
__global__ __launch_bounds__(256, 3) void attn_k(
    const u16* __restrict__ qk, const u16* __restrict__ Vt,
    u16* __restrict__ o)
{
  __shared__ __align__(16) unsigned char Ks[16384];   // [128 s][128B dk] swz
  __shared__ __align__(16) unsigned char Vs[16384];   // [64 dk][256B s] swz
  __shared__ __align__(16) unsigned char Ps[16384];   // per-wave [16 q][256B s] swz

  const int bh  = blockIdx.x;          // b*16 + h
  const int qc  = blockIdx.y;          // q chunk (64 rows)
  const int b   = bh >> 4, h = bh & 15;
  const int tid = threadIdx.x;
  const int lane = tid & 63;
  const int wv   = tid >> 6;
  const int qcol = lane & 15;
  const int g    = lane >> 4;

  const size_t rowbase = (size_t)b * Tn;
  const size_t qrow0   = rowbase + qc * 64 + wv * 16;

  // Q fragments
  bf16x8 qf[2];
  {
    const u16* qp = &qk[(qrow0 + qcol) * 2048 + h * 64 + g * 8];
    qf[0] = *reinterpret_cast<const bf16x8*>(qp);
    qf[1] = *reinterpret_cast<const bf16x8*>(qp + 32);
  }

  f32x4 oa[4] = {};
  float m_run = -3e38f, l_run = 0.f;

  // staging lanes
  const int krow = tid >> 3, kch = tid & 7;                 // K: 32 rows/issue
  const int vrow = tid >> 4, vch = tid & 15;                // V: 16 rows/issue
  char* lK = (char*)Ks + wv * 1024;
  char* lV = (char*)Vs + wv * 1024;
  unsigned char* Pw = &Ps[wv * 4096];

  for (int c = 0; c < 4; c++) {
    __syncthreads();   // previous chunk's LDS reads complete
    // stage K chunk [128 s][64 dk]
#pragma unroll
    for (int i = 0; i < 4; i++) {
      int row = i * 32 + krow;
      const u16* gk = &qk[(rowbase + c * 128 + row) * 2048 + 1024 + h * 64
                          + ((kch ^ (row & 7)) << 3)];
      gl2lds16(gk, lK + i * 4096);
    }
    // stage V^T chunk [64 dk][128 s]
#pragma unroll
    for (int i = 0; i < 4; i++) {
      int row = i * 16 + vrow;
      const u16* gv = &Vt[(((size_t)bh * 64 + row) << 9) + c * 128
                          + ((vch ^ (row & 7)) << 3)];
      gl2lds16(gv, lV + i * 4096);
    }
    __syncthreads();   // staging complete

    // ---- QK^T: S^T tiles (s rows x q cols) ----
    f32x4 sf[8];
#pragma unroll
    for (int t = 0; t < 8; t++) {
      sf[t] = (f32x4){0.f, 0.f, 0.f, 0.f};
      const int srow = t * 16 + qcol;
      const int base = srow * 128;
      const int sw = srow & 7;
#pragma unroll
      for (int ks = 0; ks < 2; ks++) {
        bf16x8 a = *reinterpret_cast<const bf16x8*>(
            &Ks[base + (((ks * 4 + g) ^ sw) << 4)]);
        sf[t] = __builtin_amdgcn_mfma_f32_16x16x32_bf16(a, qf[ks], sf[t], 0, 0, 0);
      }
    }

    // ---- online softmax (row = this lane's qcol) ----
    float mc = -3e38f;
#pragma unroll
    for (int t = 0; t < 8; t++)
#pragma unroll
      for (int r = 0; r < 4; r++) {
        float s = sf[t][r] * 0.125f;
        sf[t][r] = s;
        mc = fmaxf(mc, s);
      }
    mc = fmaxf(mc, __shfl_xor(mc, 16, 64));
    mc = fmaxf(mc, __shfl_xor(mc, 32, 64));
    float mnew = fmaxf(m_run, mc);
    float alpha = __expf(m_run - mnew);
    m_run = mnew;

    float lsum = 0.f;
#pragma unroll
    for (int t = 0; t < 8; t++)
#pragma unroll
      for (int r = 0; r < 4; r++) {
        float e = __expf(sf[t][r] - mnew);
        sf[t][r] = e;
        lsum += e;
      }
    lsum += __shfl_xor(lsum, 16, 64);
    lsum += __shfl_xor(lsum, 32, 64);
    l_run = l_run * alpha + lsum;

    // rescale O accumulator (per O-row q = g*4+j)
#pragma unroll
    for (int j = 0; j < 4; j++) {
      float av = __shfl(alpha, (g << 4) + g * 4 + j, 64);
#pragma unroll
      for (int nt = 0; nt < 4; nt++) oa[nt][j] *= av;
    }

    // ---- pack P -> per-wave LDS (swizzled), wave-coherent ----
#pragma unroll
    for (int t = 0; t < 8; t++) {
      int o0 = t * 32 + g * 8;                 // byte offset of s=t*16+g*4
      int chunk = o0 >> 4;
      int sb = ((chunk ^ (qcol & 7)) << 4) | (o0 & 15);
      *reinterpret_cast<unsigned int*>(&Pw[qcol * 256 + sb]) =
          pack2bf(sf[t][0], sf[t][1]);
      *reinterpret_cast<unsigned int*>(&Pw[qcol * 256 + sb + 4]) =
          pack2bf(sf[t][2], sf[t][3]);
    }

    // ---- PV ----
    bf16x8 pa[4];
#pragma unroll
    for (int ks = 0; ks < 4; ks++)
      pa[ks] = *reinterpret_cast<const bf16x8*>(
          &Pw[qcol * 256 + (((ks * 4 + g) ^ (qcol & 7)) << 4)]);
#pragma unroll
    for (int nt = 0; nt < 4; nt++) {
      const int vr = nt * 16 + qcol;           // dk row
      const int vsw = vr & 7;
#pragma unroll
      for (int ks = 0; ks < 4; ks++) {
        bf16x8 bvf = *reinterpret_cast<const bf16x8*>(
            &Vs[vr * 256 + (((ks * 4 + g) ^ vsw) << 4)]);
        oa[nt] = __builtin_amdgcn_mfma_f32_16x16x32_bf16(pa[ks], bvf, oa[nt], 0, 0, 0);
      }
    }
  }

  // ---- normalize + write bf16 concat ----
  float rl = 1.f / l_run;
#pragma unroll
  for (int j = 0; j < 4; j++) {
    float il = __shfl(rl, (g << 4) + g * 4 + j, 64);
#pragma unroll
    for (int nt = 0; nt < 4; nt++)
      o[(qrow0 + g * 4 + j) * 1024 + h * 64 + nt * 16 + qcol] =
          f2bf(oa[nt][j] * il);
  }
}

// ---------------------------------------------------------------------------
// reduce 64 partial col sums -> scale/shift
// ---------------------------------------------------------------------------
__global__ __launch_bounds__(256) void reduce_stats_k(
    const float* __restrict__ ps, const float* __restrict__ pq,
    const float* __restrict__ g, const float* __restrict__ be,
    float* __restrict__ scale, float* __restrict__ shift)
{
  const int col = blockIdx.x * 256 + threadIdx.x;
  float s = 0.f, q = 0.f;
  for (int p = 0; p < 64; p++) {
    s += ps[(size_t)p * Dn + col];
    q += pq[(size_t)p * Dn + col];
  }
  const float invn = 1.f / 4096.f;
  float mean = s * invn;
  float var = q * invn - mean * mean;
  float inv = rsqrtf(var + 1e-3f);
  float sc = g[col] * inv;
  scale[col] = sc;
  shift[col] = be[col] - mean * sc;
}

template<int DUAL>
__global__ __launch_bounds__(256) void norm_k(
    const float* __restrict__ r, const float* __restrict__ scale,
    const float* __restrict__ shift, float* __restrict__ o, u16* __restrict__ ob)
{
  const size_t idx = (size_t)blockIdx.x * 256 + threadIdx.x;
  const int c4 = ((int)idx & 255) << 2;
  float4 rv = *reinterpret_cast<const float4*>(&r[idx << 2]);
  float4 sc = *reinterpret_cast<const float4*>(&scale[c4]);
  float4 sh = *reinterpret_cast<const float4*>(&shift[c4]);
  float4 ov = make_float4(fmaf(rv.x, sc.x, sh.x), fmaf(rv.y, sc.y, sh.y),
                          fmaf(rv.z, sc.z, sh.z), fmaf(rv.w, sc.w, sh.w));
  *reinterpret_cast<float4*>(&o[idx << 2]) = ov;
  if (DUAL) {
    uint2 p;
    p.x = pack2bf(ov.x, ov.y);
    p.y = pack2bf(ov.z, ov.w);
    *reinterpret_cast<uint2*>(&ob[idx << 2]) = p;
  }
}

// ---------------------------------------------------------------------------
extern "C" void kernel_launch(void* const* d_in, const int* in_sizes, int n_in,
                              void* d_out, int out_size, void* d_ws, size_t ws_size,
                              hipStream_t stream)
{
  const float* x   = (const float*)d_in[0];
  const float* wq  = (const float*)d_in[1];
  const float* wk  = (const float*)d_in[2];
  const float* wv  = (const float*)d_in[3];
  const float* W   = (const float*)d_in[4];
  const float* W1  = (const float*)d_in[5];
  const float* b1  = (const float*)d_in[6];
  const float* W2  = (const float*)d_in[7];
  const float* b2  = (const float*)d_in[8];
  const float* g1  = (const float*)d_in[9];
  const float* be1 = (const float*)d_in[10];
  const float* g2  = (const float*)d_in[11];
  const float* be2 = (const float*)d_in[12];

  float* out = (float*)d_out;
  float* ws  = (float*)d_ws;

  const size_t NB = (size_t)Mn * Dn;   // 4M
  float* ws1    = ws;                  // r (fp32)
  float* ws2    = ws1 + NB;            // out1 (fp32)
  float* psum   = ws2 + NB;            // 64*1024
  float* psumsq = psum + 64 * Dn;
  float* scale  = psumsq + 64 * Dn;
  float* shift  = scale + Dn;
  u16* xb      = (u16*)(shift + Dn);   // 4M
  u16* qkb     = xb + NB;              // 8M  [4096][2048]
  u16* vtb     = qkb + 2 * NB;         // 4M  [(b,h)][64][512]
  u16* concatb = vtb + NB;             // 4M
  u16* wqkvT   = concatb + NB;         // 3M
  u16* wt      = wqkvT + 3 * 1048576;
  u16* w1t     = wt + 1048576;
  u16* w2t     = w1t + 1048576;
  // aliases (qkb dead after attn):
  u16* out1b = qkb;
  u16* hb    = qkb + NB;

  dim3 b256(256), b512(512);

  // 0. converts / transposes
  cvt_bf16_k<<<dim3(2048), b256, 0, stream>>>(x, xb);
  tqkv_k<<<dim3(16, 48), b256, 0, stream>>>(wq, wk, wv, wqkvT);
  tw_k<<<dim3(16, 16, 3), b256, 0, stream>>>(W, W1, W2, wt, w1t, w2t);

  // 1. qkv = x @ [Wq|Wk|Wv]; q,k -> qkb (ldc 2048), V -> vtb transposed
  mgemm_k<0, 0, 1, 0, 1><<<dim3(24, 32), b512, 0, stream>>>(
      xb, wqkvT, nullptr, nullptr, qkb, 2048,
      nullptr, nullptr, nullptr, nullptr, vtb);
  // 2. flash attention -> concat bf16
  attn_k<<<dim3(128, 8), b256, 0, stream>>>(qkb, vtb, concatb);
  // 3. r1 = x + concat @ W -> ws1 (+stats fused)
  mgemm_k<0, 0, 2, 1, 0><<<dim3(8, 32), b512, 0, stream>>>(
      concatb, wt, nullptr, nullptr, nullptr, 1024,
      x, ws1, psum, psumsq, nullptr);
  reduce_stats_k<<<dim3(4), b256, 0, stream>>>(psum, psumsq, g1, be1, scale, shift);
  // 4. out1 = BN1(r1) -> ws2 (fp32) + out1b (bf16)
  norm_k<1><<<dim3(NB / 1024), b256, 0, stream>>>(ws1, scale, shift, ws2, out1b);
  // 5. h = relu(out1 @ W1 + b1) -> bf16
  mgemm_k<1, 1, 1, 0, 0><<<dim3(8, 32), b512, 0, stream>>>(
      out1b, w1t, b1, nullptr, hb, 1024,
      nullptr, nullptr, nullptr, nullptr, nullptr);
  // 6. r2 = out1 + (h @ W2 + b2) -> ws1 (+stats fused)
  mgemm_k<1, 0, 2, 1, 0><<<dim3(8, 32), b512, 0, stream>>>(
      hb, w2t, b2, nullptr, nullptr, 1024,
      ws2, ws1, psum, psumsq, nullptr);
  reduce_stats_k<<<dim3(4), b256, 0, stream>>>(psum, psumsq, g2, be2, scale, shift);
  // 7. final BN -> d_out
  norm_k<0><<<dim3(NB / 1024), b256, 0, stream>>>(ws1, scale, shift, out, nullptr);
}

// Round 5
// 174.773 us; speedup vs baseline: 10.0416x; 1.0610x over previous
//
#include <hip/hip_runtime.h>
#include <hip/hip_bf16.h>
#include <cstdint>

#define Bn 8
#define Tn 512
#define Dn 1024
#define Hn 16
#define DKn 64
#define Mn (Bn * Tn)   // 4096

typedef unsigned short u16;
typedef short bf16x8 __attribute__((ext_vector_type(8)));
typedef float f32x4 __attribute__((ext_vector_type(4)));

__device__ __forceinline__ u16 f2bf(float f) {
  unsigned int u = __builtin_bit_cast(unsigned int, f);
  u += 0x7fffu + ((u >> 16) & 1u);
  return (u16)(u >> 16);
}
__device__ __forceinline__ unsigned int pack2bf(float lo, float hi) {
  return (unsigned int)f2bf(lo) | ((unsigned int)f2bf(hi) << 16);
}

// async global->LDS, 16B per lane; lds ptr wave-uniform + lane*16.
__device__ __forceinline__ void gl2lds16(const void* g, void* l) {
  __builtin_amdgcn_global_load_lds(
      (const __attribute__((address_space(1))) unsigned int*)g,
      (__attribute__((address_space(3))) unsigned int*)l,
      16, 0, 0);
}

// ---------------------------------------------------------------------------
// fp32 -> bf16 elementwise
// ---------------------------------------------------------------------------
__global__ __launch_bounds__(256) void cvt_bf16_k(
    const float* __restrict__ src, u16* __restrict__ dst)
{
  const size_t i = ((size_t)blockIdx.x * 256 + threadIdx.x) * 8;
  float4 a = *reinterpret_cast<const float4*>(&src[i]);
  float4 b = *reinterpret_cast<const float4*>(&src[i + 4]);
  uint4 w;
  w.x = pack2bf(a.x, a.y); w.y = pack2bf(a.z, a.w);
  w.z = pack2bf(b.x, b.y); w.w = pack2bf(b.z, b.w);
  *reinterpret_cast<uint4*>(&dst[i]) = w;
}

// ---------------------------------------------------------------------------
// Transpose+convert QKV weights (H,D,DK) fp32 -> WqkvT[3072][1024] bf16.
// ---------------------------------------------------------------------------
__global__ __launch_bounds__(256) void tqkv_k(
    const float* __restrict__ wq, const float* __restrict__ wk,
    const float* __restrict__ wv, u16* __restrict__ dst)
{
  const int kt = blockIdx.x;
  const int y  = blockIdx.y;
  const int tau = y >> 4, head = y & 15;
  const float* src = (tau == 0 ? wq : tau == 1 ? wk : wv) + (size_t)head * 65536;
  const int t = threadIdx.x;
  const int n  = t & 63;
  const int kq = (t >> 6) << 4;
  const int k0 = kt << 6;
  u16 v[16];
#pragma unroll
  for (int j = 0; j < 16; j++)
    v[j] = f2bf(src[(size_t)(k0 + kq + j) * 64 + n]);
  u16* d = &dst[((size_t)tau * 1024 + head * 64 + n) * 1024 + k0 + kq];
  *reinterpret_cast<uint4*>(&d[0]) = *reinterpret_cast<uint4*>(&v[0]);
  *reinterpret_cast<uint4*>(&d[8]) = *reinterpret_cast<uint4*>(&v[8]);
}

// W/W1/W2 [1024][1024] fp32 -> [N][K] bf16 transposed
__global__ __launch_bounds__(256) void tw_k(
    const float* __restrict__ W, const float* __restrict__ W1,
    const float* __restrict__ W2, u16* __restrict__ wt,
    u16* __restrict__ w1t, u16* __restrict__ w2t)
{
  const int kt = blockIdx.x, ntl = blockIdx.y, z = blockIdx.z;
  const float* src = (z == 0 ? W : z == 1 ? W1 : W2);
  u16* dst = (z == 0 ? wt : z == 1 ? w1t : w2t);
  const int t = threadIdx.x;
  const int n  = (ntl << 6) + (t & 63);
  const int kq = (t >> 6) << 4;
  const int k0 = kt << 6;
  u16 v[16];
#pragma unroll
  for (int j = 0; j < 16; j++)
    v[j] = f2bf(src[(size_t)(k0 + kq + j) * 1024 + n]);
  u16* d = &dst[(size_t)n * 1024 + k0 + kq];
  *reinterpret_cast<uint4*>(&d[0]) = *reinterpret_cast<uint4*>(&v[0]);
  *reinterpret_cast<uint4*>(&d[8]) = *reinterpret_cast<uint4*>(&v[8]);
}

// ---------------------------------------------------------------------------
// bf16 MFMA GEMM: C[M,N] = A[M,1024] @ Bt[N,1024]^T. Tile 128x128, BK=32,
// 8 waves, double-buffered LDS with 2-phase prefetch (T3 minimum recipe),
// XCD-chunked block swizzle. OUTM: 0=fp32, 1=bf16, 2=none.
// RES: r = acc(+bias) + res -> Rout(fp32) + partial col stats.
//   RESNORM: res = BN(Rres) on the fly (Rres raw + nsc/nsh).
// VT: blocks bx>=16 write V transposed into Vt[(b,h)][dk][512].
// ---------------------------------------------------------------------------
template<int BIAS, int RELU, int OUTM, int RES, int VT, int RESNORM>
__global__ __launch_bounds__(512) void mgemm_k(
    const u16* __restrict__ A, const u16* __restrict__ Bt,
    const float* __restrict__ bias,
    float* __restrict__ Cf, u16* __restrict__ Cb, int ldc,
    const float* __restrict__ Rres, float* __restrict__ Rout,
    float* __restrict__ psum, float* __restrict__ psumsq,
    u16* __restrict__ Vt,
    const float* __restrict__ nsc, const float* __restrict__ nsh)
{
  __shared__ __align__(16) u16 As[2][4096];   // [buf][128 rows][32 k]
  __shared__ __align__(16) u16 Bs[2][4096];

  // XCD-chunked bijective swizzle (nwg % 8 == 0 for all our grids)
  const int nwg = gridDim.x * gridDim.y;
  const int fid = blockIdx.y * gridDim.x + blockIdx.x;
  const int lid = (fid & 7) * (nwg >> 3) + (fid >> 3);
  const int bx = lid % gridDim.x, by = lid / gridDim.x;

  const int tid  = threadIdx.x;
  const int lane = tid & 63;
  const int wid  = tid >> 6;
  const int wm = wid >> 2, wn = wid & 3;
  const int g4 = lane >> 4, r15 = lane & 15;
  const int m0 = by << 7, n0 = bx << 7;

  const int srow  = tid >> 2;
  const int sslot = tid & 3;
  const int ssw   = (srow ^ (srow >> 2)) & 3;
  const int sk8   = ((sslot ^ ssw) << 3);
  const u16* ga0 = &A[(size_t)(m0 + srow) * 1024 + sk8];
  const u16* gb0 = &Bt[(size_t)(n0 + srow) * 1024 + sk8];
  const int lofs = wid * 1024;   // per-wave byte offset into a buffer

  f32x4 acc[4][2] = {};

  // prologue: stage tile 0 into buf 0
  gl2lds16(ga0, (char*)As[0] + lofs);
  gl2lds16(gb0, (char*)Bs[0] + lofs);
  __syncthreads();

#pragma unroll 1
  for (int t = 0; t < 32; t++) {
    const int cur = t & 1;
    if (t < 31) {   // prefetch next tile into other buffer
      gl2lds16(ga0 + (t + 1) * 32, (char*)As[cur ^ 1] + lofs);
      gl2lds16(gb0 + (t + 1) * 32, (char*)Bs[cur ^ 1] + lofs);
    }
    bf16x8 af[4], bfr[2];
#pragma unroll
    for (int m = 0; m < 4; m++) {
      int row = wm * 64 + m * 16 + r15;
      int sw = (row ^ (row >> 2)) & 3;
      af[m] = *reinterpret_cast<const bf16x8*>(
          (const char*)As[cur] + row * 64 + ((g4 ^ sw) << 4));
    }
#pragma unroll
    for (int n = 0; n < 2; n++) {
      int row = wn * 32 + n * 16 + r15;
      int sw = (row ^ (row >> 2)) & 3;
      bfr[n] = *reinterpret_cast<const bf16x8*>(
          (const char*)Bs[cur] + row * 64 + ((g4 ^ sw) << 4));
    }
#pragma unroll
    for (int m = 0; m < 4; m++)
#pragma unroll
      for (int n = 0; n < 2; n++)
        acc[m][n] = __builtin_amdgcn_mfma_f32_16x16x32_bf16(af[m], bfr[n], acc[m][n], 0, 0, 0);
    __syncthreads();   // drains prefetch (vmcnt) + LDS reads, then swap
  }

  // ---- VT epilogue: write V transposed ----
  if (VT && bx >= 16) {
    const int vcol0 = n0 - 2048;
#pragma unroll
    for (int m = 0; m < 4; m++) {
      int row0 = m0 + wm * 64 + m * 16 + g4 * 4;
      int bI = row0 >> 9, s = row0 & 511;
#pragma unroll
      for (int n = 0; n < 2; n++) {
        int cv = vcol0 + wn * 32 + n * 16 + r15;
        int hh = cv >> 6, dk = cv & 63;
        uint2 pk;
        pk.x = pack2bf(acc[m][n][0], acc[m][n][1]);
        pk.y = pack2bf(acc[m][n][2], acc[m][n][3]);
        *reinterpret_cast<uint2*>(
            &Vt[(((size_t)(bI * 16 + hh) * 64 + dk) << 9) + s]) = pk;
      }
    }
    return;
  }

  float bb[2] = {0.f, 0.f};
  if (BIAS) {
#pragma unroll
    for (int n = 0; n < 2; n++) bb[n] = bias[n0 + wn * 32 + n * 16 + r15];
  }

  if (RES) {
    float sc_[2], sh_[2];
    if (RESNORM) {
#pragma unroll
      for (int n = 0; n < 2; n++) {
        int col = n0 + wn * 32 + n * 16 + r15;
        sc_[n] = nsc[col];
        sh_[n] = nsh[col];
      }
    }
    float sp[2] = {0.f, 0.f}, sq[2] = {0.f, 0.f};
#pragma unroll
    for (int m = 0; m < 4; m++) {
      int row = m0 + wm * 64 + m * 16 + g4 * 4;
#pragma unroll
      for (int n = 0; n < 2; n++) {
        int col = n0 + wn * 32 + n * 16 + r15;
#pragma unroll
        for (int j = 0; j < 4; j++) {
          float v = acc[m][n][j] + bb[n];
          float res = Rres[(size_t)(row + j) * 1024 + col];
          if (RESNORM) res = fmaf(res, sc_[n], sh_[n]);
          float r = v + res;
          Rout[(size_t)(row + j) * 1024 + col] = r;
          sp[n] += r;
          sq[n] = fmaf(r, r, sq[n]);
        }
      }
    }
#pragma unroll
    for (int n = 0; n < 2; n++) {
      sp[n] += __shfl_xor(sp[n], 16, 64);
      sp[n] += __shfl_xor(sp[n], 32, 64);
      sq[n] += __shfl_xor(sq[n], 16, 64);
      sq[n] += __shfl_xor(sq[n], 32, 64);
    }
    if (g4 == 0) {
      int slot = (by << 1) + wm;
#pragma unroll
      for (int n = 0; n < 2; n++) {
        int col = n0 + wn * 32 + n * 16 + r15;
        psum[(size_t)slot * 1024 + col] = sp[n];
        psumsq[(size_t)slot * 1024 + col] = sq[n];
      }
    }
    return;
  }

#pragma unroll
  for (int m = 0; m < 4; m++) {
    int row = m0 + wm * 64 + m * 16 + g4 * 4;
#pragma unroll
    for (int n = 0; n < 2; n++) {
      int col = n0 + wn * 32 + n * 16 + r15;
#pragma unroll
      for (int j = 0; j < 4; j++) {
        float v = acc[m][n][j];
        if (BIAS) v += bb[n];
        if (RELU) v = fmaxf(v, 0.f);
        if (OUTM == 1)      Cb[(size_t)(row + j) * ldc + col] = f2bf(v);
        else if (OUTM == 0) Cf[(size_t)(row + j) * ldc + col] = v;
      }
    }
  }
}

// ---------------------------------------------------------------------------
// Flash MFMA attention, double-buffered K/V staging.
// Grid (bh=128, qchunk=8); block = 64 q-rows (4 waves).
// qk: [4096][2048] bf16 (q|k slabs). Vt: [(b,h)][64][512] bf16.
// ---------------------------------------------------------------------------
__global__ __launch_bounds__(256, 2) void attn_k(
    const u16* __restrict__ qk, const u16* __restrict__ Vt,
    u16* __restrict__ o)
{
  __shared__ __align__(16) unsigned char Ks[2][16384];  // [128 s][128B dk] swz
  __shared__ __align__(16) unsigned char Vs[2][16384];  // [64 dk][256B s] swz
  __shared__ __align__(16) unsigned char Ps[16384];     // per-wave [16 q][256B s]

  const int bh  = blockIdx.x;
  const int qc  = blockIdx.y;
  const int b   = bh >> 4, h = bh & 15;
  const int tid = threadIdx.x;
  const int lane = tid & 63;
  const int wv   = tid >> 6;
  const int qcol = lane & 15;
  const int g    = lane >> 4;

  const size_t rowbase = (size_t)b * Tn;
  const size_t qrow0   = rowbase + qc * 64 + wv * 16;

  bf16x8 qf[2];
  {
    const u16* qp = &qk[(qrow0 + qcol) * 2048 + h * 64 + g * 8];
    qf[0] = *reinterpret_cast<const bf16x8*>(qp);
    qf[1] = *reinterpret_cast<const bf16x8*>(qp + 32);
  }

  f32x4 oa[4] = {};
  float m_run = -3e38f, l_run = 0.f;

  const int krow = tid >> 3, kch = tid & 7;
  const int vrow = tid >> 4, vch = tid & 15;
  unsigned char* Pw = &Ps[wv * 4096];

#define STAGE_KV(c_, buf_)                                                     \
  {                                                                            \
    _Pragma("unroll")                                                          \
    for (int i = 0; i < 4; i++) {                                              \
      int row = i * 32 + krow;                                                 \
      const u16* gk = &qk[(rowbase + (c_) * 128 + row) * 2048 + 1024 + h * 64  \
                          + ((kch ^ (row & 7)) << 3)];                         \
      gl2lds16(gk, (char*)Ks[buf_] + wv * 1024 + i * 4096);                    \
    }                                                                          \
    _Pragma("unroll")                                                          \
    for (int i = 0; i < 4; i++) {                                              \
      int row = i * 16 + vrow;                                                 \
      const u16* gv = &Vt[(((size_t)bh * 64 + row) << 9) + (c_) * 128          \
                          + ((vch ^ (row & 7)) << 3)];                         \
      gl2lds16(gv, (char*)Vs[buf_] + wv * 1024 + i * 4096);                    \
    }                                                                          \
  }

  STAGE_KV(0, 0);
  __syncthreads();

#pragma unroll 1
  for (int c = 0; c < 4; c++) {
    const int cur = c & 1;
    if (c < 3) STAGE_KV(c + 1, cur ^ 1);

    // ---- QK^T: S^T tiles ----
    f32x4 sf[8];
#pragma unroll
    for (int t = 0; t < 8; t++) {
      sf[t] = (f32x4){0.f, 0.f, 0.f, 0.f};
      const int srow = t * 16 + qcol;
      const int base = srow * 128;
      const int sw = srow & 7;
#pragma unroll
      for (int ks = 0; ks < 2; ks++) {
        bf16x8 a = *reinterpret_cast<const bf16x8*>(
            &Ks[cur][base + (((ks * 4 + g) ^ sw) << 4)]);
        sf[t] = __builtin_amdgcn_mfma_f32_16x16x32_bf16(a, qf[ks], sf[t], 0, 0, 0);
      }
    }

    // ---- online softmax ----
    float mc = -3e38f;
#pragma unroll
    for (int t = 0; t < 8; t++)
#pragma unroll
      for (int r = 0; r < 4; r++) {
        float s = sf[t][r] * 0.125f;
        sf[t][r] = s;
        mc = fmaxf(mc, s);
      }
    mc = fmaxf(mc, __shfl_xor(mc, 16, 64));
    mc = fmaxf(mc, __shfl_xor(mc, 32, 64));
    float mnew = fmaxf(m_run, mc);
    float alpha = __expf(m_run - mnew);
    m_run = mnew;

    float lsum = 0.f;
#pragma unroll
    for (int t = 0; t < 8; t++)
#pragma unroll
      for (int r = 0; r < 4; r++) {
        float e = __expf(sf[t][r] - mnew);
        sf[t][r] = e;
        lsum += e;
      }
    lsum += __shfl_xor(lsum, 16, 64);
    lsum += __shfl_xor(lsum, 32, 64);
    l_run = l_run * alpha + lsum;

#pragma unroll
    for (int j = 0; j < 4; j++) {
      float av = __shfl(alpha, (g << 4) + g * 4 + j, 64);
#pragma unroll
      for (int nt = 0; nt < 4; nt++) oa[nt][j] *= av;
    }

    // ---- pack P -> per-wave LDS (swizzled) ----
#pragma unroll
    for (int t = 0; t < 8; t++) {
      int o0 = t * 32 + g * 8;
      int chunk = o0 >> 4;
      int sb = ((chunk ^ (qcol & 7)) << 4) | (o0 & 15);
      *reinterpret_cast<unsigned int*>(&Pw[qcol * 256 + sb]) =
          pack2bf(sf[t][0], sf[t][1]);
      *reinterpret_cast<unsigned int*>(&Pw[qcol * 256 + sb + 4]) =
          pack2bf(sf[t][2], sf[t][3]);
    }

    // ---- PV ----
    bf16x8 pa[4];
#pragma unroll
    for (int ks = 0; ks < 4; ks++)
      pa[ks] = *reinterpret_cast<const bf16x8*>(
          &Pw[qcol * 256 + (((ks * 4 + g) ^ (qcol & 7)) << 4)]);
#pragma unroll
    for (int nt = 0; nt < 4; nt++) {
      const int vr = nt * 16 + qcol;
      const int vsw = vr & 7;
#pragma unroll
      for (int ks = 0; ks < 4; ks++) {
        bf16x8 bvf = *reinterpret_cast<const bf16x8*>(
            &Vs[cur][vr * 256 + (((ks * 4 + g) ^ vsw) << 4)]);
        oa[nt] = __builtin_amdgcn_mfma_f32_16x16x32_bf16(pa[ks], bvf, oa[nt], 0, 0, 0);
      }
    }
    __syncthreads();   // drains prefetch + this chunk's LDS reads
  }

  float rl = 1.f / l_run;
#pragma unroll
  for (int j = 0; j < 4; j++) {
    float il = __shfl(rl, (g << 4) + g * 4 + j, 64);
#pragma unroll
    for (int nt = 0; nt < 4; nt++)
      o[(qrow0 + g * 4 + j) * 1024 + h * 64 + nt * 16 + qcol] =
          f2bf(oa[nt][j] * il);
  }
#undef STAGE_KV
}

// ---------------------------------------------------------------------------
__global__ __launch_bounds__(256) void reduce_stats_k(
    const float* __restrict__ ps, const float* __restrict__ pq,
    const float* __restrict__ g, const float* __restrict__ be,
    float* __restrict__ scale, float* __restrict__ shift)
{
  const int col = blockIdx.x * 256 + threadIdx.x;
  float s = 0.f, q = 0.f;
  for (int p = 0; p < 64; p++) {
    s += ps[(size_t)p * Dn + col];
    q += pq[(size_t)p * Dn + col];
  }
  const float invn = 1.f / 4096.f;
  float mean = s * invn;
  float var = q * invn - mean * mean;
  float inv = rsqrtf(var + 1e-3f);
  float sc = g[col] * inv;
  scale[col] = sc;
  shift[col] = be[col] - mean * sc;
}

// OUTMODE: 0 = fp32 only, 2 = bf16 only
template<int OUTMODE>
__global__ __launch_bounds__(256) void norm_k(
    const float* __restrict__ r, const float* __restrict__ scale,
    const float* __restrict__ shift, float* __restrict__ o, u16* __restrict__ ob)
{
  const size_t idx = (size_t)blockIdx.x * 256 + threadIdx.x;
  const int c4 = ((int)idx & 255) << 2;
  float4 rv = *reinterpret_cast<const float4*>(&r[idx << 2]);
  float4 sc = *reinterpret_cast<const float4*>(&scale[c4]);
  float4 sh = *reinterpret_cast<const float4*>(&shift[c4]);
  float4 ov = make_float4(fmaf(rv.x, sc.x, sh.x), fmaf(rv.y, sc.y, sh.y),
                          fmaf(rv.z, sc.z, sh.z), fmaf(rv.w, sc.w, sh.w));
  if (OUTMODE == 0) {
    *reinterpret_cast<float4*>(&o[idx << 2]) = ov;
  } else {
    uint2 p;
    p.x = pack2bf(ov.x, ov.y);
    p.y = pack2bf(ov.z, ov.w);
    *reinterpret_cast<uint2*>(&ob[idx << 2]) = p;
  }
}

// ---------------------------------------------------------------------------
extern "C" void kernel_launch(void* const* d_in, const int* in_sizes, int n_in,
                              void* d_out, int out_size, void* d_ws, size_t ws_size,
                              hipStream_t stream)
{
  const float* x   = (const float*)d_in[0];
  const float* wq  = (const float*)d_in[1];
  const float* wk  = (const float*)d_in[2];
  const float* wv  = (const float*)d_in[3];
  const float* W   = (const float*)d_in[4];
  const float* W1  = (const float*)d_in[5];
  const float* b1  = (const float*)d_in[6];
  const float* W2  = (const float*)d_in[7];
  const float* b2  = (const float*)d_in[8];
  const float* g1  = (const float*)d_in[9];
  const float* be1 = (const float*)d_in[10];
  const float* g2  = (const float*)d_in[11];
  const float* be2 = (const float*)d_in[12];

  float* out = (float*)d_out;
  float* ws  = (float*)d_ws;

  const size_t NB = (size_t)Mn * Dn;   // 4M
  float* ws1    = ws;                  // r1 (fp32)
  float* ws2    = ws1 + NB;            // r2 (fp32)
  float* psum   = ws2 + NB;            // 64*1024
  float* psumsq = psum + 64 * Dn;
  float* scale1 = psumsq + 64 * Dn;
  float* shift1 = scale1 + Dn;
  float* scale2 = shift1 + Dn;
  float* shift2 = scale2 + Dn;
  u16* xb      = (u16*)(shift2 + Dn);  // 4M
  u16* qkb     = xb + NB;              // 8M  [4096][2048]
  u16* vtb     = qkb + 2 * NB;         // 4M  [(b,h)][64][512]
  u16* concatb = vtb + NB;             // 4M
  u16* wqkvT   = concatb + NB;         // 3M
  u16* wt      = wqkvT + 3 * 1048576;
  u16* w1t     = wt + 1048576;
  u16* w2t     = w1t + 1048576;
  // aliases (qkb dead after attn):
  u16* out1b = qkb;
  u16* hb    = qkb + NB;

  dim3 b256(256), b512(512);

  // 0. converts / transposes
  cvt_bf16_k<<<dim3(2048), b256, 0, stream>>>(x, xb);
  tqkv_k<<<dim3(16, 48), b256, 0, stream>>>(wq, wk, wv, wqkvT);
  tw_k<<<dim3(16, 16, 3), b256, 0, stream>>>(W, W1, W2, wt, w1t, w2t);

  // 1. qkv = x @ [Wq|Wk|Wv]; q,k -> qkb (ldc 2048), V -> vtb transposed
  mgemm_k<0, 0, 1, 0, 1, 0><<<dim3(24, 32), b512, 0, stream>>>(
      xb, wqkvT, nullptr, nullptr, qkb, 2048,
      nullptr, nullptr, nullptr, nullptr, vtb, nullptr, nullptr);
  // 2. flash attention -> concat bf16
  attn_k<<<dim3(128, 8), b256, 0, stream>>>(qkb, vtb, concatb);
  // 3. r1 = x + concat @ W -> ws1 (+stats fused)
  mgemm_k<0, 0, 2, 1, 0, 0><<<dim3(8, 32), b512, 0, stream>>>(
      concatb, wt, nullptr, nullptr, nullptr, 1024,
      x, ws1, psum, psumsq, nullptr, nullptr, nullptr);
  reduce_stats_k<<<dim3(4), b256, 0, stream>>>(psum, psumsq, g1, be1, scale1, shift1);
  // 4. out1b = BN1(r1) bf16 (fp32 copy not needed; GEMM6 re-derives it)
  norm_k<2><<<dim3(NB / 1024), b256, 0, stream>>>(ws1, scale1, shift1, nullptr, out1b);
  // 5. h = relu(out1 @ W1 + b1) -> bf16
  mgemm_k<1, 1, 1, 0, 0, 0><<<dim3(8, 32), b512, 0, stream>>>(
      out1b, w1t, b1, nullptr, hb, 1024,
      nullptr, nullptr, nullptr, nullptr, nullptr, nullptr, nullptr);
  // 6. r2 = BN1(r1) + (h @ W2 + b2) -> ws2 (+stats fused)
  mgemm_k<1, 0, 2, 1, 0, 1><<<dim3(8, 32), b512, 0, stream>>>(
      hb, w2t, b2, nullptr, nullptr, 1024,
      ws1, ws2, psum, psumsq, nullptr, scale1, shift1);
  reduce_stats_k<<<dim3(4), b256, 0, stream>>>(psum, psumsq, g2, be2, scale2, shift2);
  // 7. final BN -> d_out
  norm_k<0><<<dim3(NB / 1024), b256, 0, stream>>>(ws2, scale2, shift2, out, nullptr);
}

// Round 6
// 171.859 us; speedup vs baseline: 10.2119x; 1.0170x over previous
//
#include <hip/hip_runtime.h>
#include <hip/hip_bf16.h>
#include <cstdint>

#define Bn 8
#define Tn 512
#define Dn 1024
#define Hn 16
#define DKn 64
#define Mn (Bn * Tn)   // 4096

typedef unsigned short u16;
typedef short bf16x8 __attribute__((ext_vector_type(8)));
typedef float f32x4 __attribute__((ext_vector_type(4)));

__device__ __forceinline__ u16 f2bf(float f) {
  unsigned int u = __builtin_bit_cast(unsigned int, f);
  u += 0x7fffu + ((u >> 16) & 1u);
  return (u16)(u >> 16);
}
__device__ __forceinline__ unsigned int pack2bf(float lo, float hi) {
  return (unsigned int)f2bf(lo) | ((unsigned int)f2bf(hi) << 16);
}

// async global->LDS, 16B per lane; lds ptr wave-uniform + lane*16.
__device__ __forceinline__ void gl2lds16(const void* g, void* l) {
  __builtin_amdgcn_global_load_lds(
      (const __attribute__((address_space(1))) unsigned int*)g,
      (__attribute__((address_space(3))) unsigned int*)l,
      16, 0, 0);
}

// raw workgroup barrier WITHOUT the vmcnt(0) drain __syncthreads implies.
// sched_barrier fences keep LDS reads from drifting across it.
__device__ __forceinline__ void hard_barrier() {
  __builtin_amdgcn_sched_barrier(0);
  __builtin_amdgcn_s_barrier();
  __builtin_amdgcn_sched_barrier(0);
}
#define WAITV(n_) asm volatile("s_waitcnt vmcnt(" #n_ ")" ::: "memory")

// ---------------------------------------------------------------------------
// fp32 -> bf16 elementwise
// ---------------------------------------------------------------------------
__global__ __launch_bounds__(256) void cvt_bf16_k(
    const float* __restrict__ src, u16* __restrict__ dst)
{
  const size_t i = ((size_t)blockIdx.x * 256 + threadIdx.x) * 8;
  float4 a = *reinterpret_cast<const float4*>(&src[i]);
  float4 b = *reinterpret_cast<const float4*>(&src[i + 4]);
  uint4 w;
  w.x = pack2bf(a.x, a.y); w.y = pack2bf(a.z, a.w);
  w.z = pack2bf(b.x, b.y); w.w = pack2bf(b.z, b.w);
  *reinterpret_cast<uint4*>(&dst[i]) = w;
}

// ---------------------------------------------------------------------------
// Transpose+convert QKV weights (H,D,DK) fp32 -> WqkvT[3072][1024] bf16.
// ---------------------------------------------------------------------------
__global__ __launch_bounds__(256) void tqkv_k(
    const float* __restrict__ wq, const float* __restrict__ wk,
    const float* __restrict__ wv, u16* __restrict__ dst)
{
  const int kt = blockIdx.x;
  const int y  = blockIdx.y;
  const int tau = y >> 4, head = y & 15;
  const float* src = (tau == 0 ? wq : tau == 1 ? wk : wv) + (size_t)head * 65536;
  const int t = threadIdx.x;
  const int n  = t & 63;
  const int kq = (t >> 6) << 4;
  const int k0 = kt << 6;
  u16 v[16];
#pragma unroll
  for (int j = 0; j < 16; j++)
    v[j] = f2bf(src[(size_t)(k0 + kq + j) * 64 + n]);
  u16* d = &dst[((size_t)tau * 1024 + head * 64 + n) * 1024 + k0 + kq];
  *reinterpret_cast<uint4*>(&d[0]) = *reinterpret_cast<uint4*>(&v[0]);
  *reinterpret_cast<uint4*>(&d[8]) = *reinterpret_cast<uint4*>(&v[8]);
}

// W/W1/W2 [1024][1024] fp32 -> [N][K] bf16 transposed
__global__ __launch_bounds__(256) void tw_k(
    const float* __restrict__ W, const float* __restrict__ W1,
    const float* __restrict__ W2, u16* __restrict__ wt,
    u16* __restrict__ w1t, u16* __restrict__ w2t)
{
  const int kt = blockIdx.x, ntl = blockIdx.y, z = blockIdx.z;
  const float* src = (z == 0 ? W : z == 1 ? W1 : W2);
  u16* dst = (z == 0 ? wt : z == 1 ? w1t : w2t);
  const int t = threadIdx.x;
  const int n  = (ntl << 6) + (t & 63);
  const int kq = (t >> 6) << 4;
  const int k0 = kt << 6;
  u16 v[16];
#pragma unroll
  for (int j = 0; j < 16; j++)
    v[j] = f2bf(src[(size_t)(k0 + kq + j) * 1024 + n]);
  u16* d = &dst[(size_t)n * 1024 + k0 + kq];
  *reinterpret_cast<uint4*>(&d[0]) = *reinterpret_cast<uint4*>(&v[0]);
  *reinterpret_cast<uint4*>(&d[8]) = *reinterpret_cast<uint4*>(&v[8]);
}

// ---------------------------------------------------------------------------
// bf16 MFMA GEMM: C[M,N] = A[M,1024] @ Bt[N,1024]^T. Tile 128x128, BK=32,
// 8 waves. Ring-of-3 LDS buffers, 2-deep global_load_lds prefetch with
// COUNTED vmcnt (never 0 in main loop) + raw s_barrier (T3+T4).
// OUTM: 0=fp32, 1=bf16, 2=none. RES/RESNORM/VT epilogues as before.
// ---------------------------------------------------------------------------
template<int BIAS, int RELU, int OUTM, int RES, int VT, int RESNORM>
__global__ __launch_bounds__(512) void mgemm_k(
    const u16* __restrict__ A, const u16* __restrict__ Bt,
    const float* __restrict__ bias,
    float* __restrict__ Cf, u16* __restrict__ Cb, int ldc,
    const float* __restrict__ Rres, float* __restrict__ Rout,
    float* __restrict__ psum, float* __restrict__ psumsq,
    u16* __restrict__ Vt,
    const float* __restrict__ nsc, const float* __restrict__ nsh)
{
  __shared__ __align__(16) u16 As[3][4096];   // 3 bufs x [128 rows][32 k]
  __shared__ __align__(16) u16 Bs[3][4096];

  // XCD-chunked bijective swizzle (nwg % 8 == 0 for all our grids)
  const int nwg = gridDim.x * gridDim.y;
  const int fid = blockIdx.y * gridDim.x + blockIdx.x;
  const int lid = (fid & 7) * (nwg >> 3) + (fid >> 3);
  const int bx = lid % gridDim.x, by = lid / gridDim.x;

  const int tid  = threadIdx.x;
  const int lane = tid & 63;
  const int wid  = tid >> 6;
  const int wm = wid >> 2, wn = wid & 3;
  const int g4 = lane >> 4, r15 = lane & 15;
  const int m0 = by << 7, n0 = bx << 7;

  const int srow  = tid >> 2;
  const int sslot = tid & 3;
  const int ssw   = (srow ^ (srow >> 2)) & 3;
  const int sk8   = ((sslot ^ ssw) << 3);
  const u16* ga0 = &A[(size_t)(m0 + srow) * 1024 + sk8];
  const u16* gb0 = &Bt[(size_t)(n0 + srow) * 1024 + sk8];
  const int lofs = wid * 1024;   // per-wave byte offset within a buffer

  f32x4 acc[4][2] = {};

  auto stage_t = [&](int t, int bofs) {
    gl2lds16(ga0 + t * 32, (char*)As + bofs + lofs);
    gl2lds16(gb0 + t * 32, (char*)Bs + bofs + lofs);
  };
  auto compute_t = [&](int bofs) {
    bf16x8 af[4], bfr[2];
#pragma unroll
    for (int m = 0; m < 4; m++) {
      int row = wm * 64 + m * 16 + r15;
      int sw = (row ^ (row >> 2)) & 3;
      af[m] = *reinterpret_cast<const bf16x8*>(
          (const char*)As + bofs + row * 64 + ((g4 ^ sw) << 4));
    }
#pragma unroll
    for (int n = 0; n < 2; n++) {
      int row = wn * 32 + n * 16 + r15;
      int sw = (row ^ (row >> 2)) & 3;
      bfr[n] = *reinterpret_cast<const bf16x8*>(
          (const char*)Bs + bofs + row * 64 + ((g4 ^ sw) << 4));
    }
#pragma unroll
    for (int m = 0; m < 4; m++)
#pragma unroll
      for (int n = 0; n < 2; n++)
        acc[m][n] = __builtin_amdgcn_mfma_f32_16x16x32_bf16(af[m], bfr[n], acc[m][n], 0, 0, 0);
  };

  // prologue: tiles 0,1 into bufs 0,1 (4 loads in flight per wave)
  stage_t(0, 0);
  stage_t(1, 8192);

  int rd = 0, wr = 2;   // read buf t%3; write buf (t+2)%3
#pragma unroll 1
  for (int t = 0; t < 30; ++t) {
    stage_t(t + 2, wr * 8192);        // +2 loads -> 6 in flight
    WAITV(4);                         // drain tile t's 2, keep 4 in flight
    hard_barrier();                   // all waves' tile-t data landed
    compute_t(rd * 8192);
    hard_barrier();                   // all waves done reading buf rd
    wr = rd;
    rd = (rd + 1 == 3) ? 0 : rd + 1;
  }
  // t = 30 (buf 0), t = 31 (buf 1)
  WAITV(2);
  hard_barrier();
  compute_t(0);
  hard_barrier();
  WAITV(0);
  hard_barrier();
  compute_t(8192);

  // ---- VT epilogue: write V transposed ----
  if (VT && bx >= 16) {
    const int vcol0 = n0 - 2048;
#pragma unroll
    for (int m = 0; m < 4; m++) {
      int row0 = m0 + wm * 64 + m * 16 + g4 * 4;
      int bI = row0 >> 9, s = row0 & 511;
#pragma unroll
      for (int n = 0; n < 2; n++) {
        int cv = vcol0 + wn * 32 + n * 16 + r15;
        int hh = cv >> 6, dk = cv & 63;
        uint2 pk;
        pk.x = pack2bf(acc[m][n][0], acc[m][n][1]);
        pk.y = pack2bf(acc[m][n][2], acc[m][n][3]);
        *reinterpret_cast<uint2*>(
            &Vt[(((size_t)(bI * 16 + hh) * 64 + dk) << 9) + s]) = pk;
      }
    }
    return;
  }

  float bb[2] = {0.f, 0.f};
  if (BIAS) {
#pragma unroll
    for (int n = 0; n < 2; n++) bb[n] = bias[n0 + wn * 32 + n * 16 + r15];
  }

  if (RES) {
    float sc_[2], sh_[2];
    if (RESNORM) {
#pragma unroll
      for (int n = 0; n < 2; n++) {
        int col = n0 + wn * 32 + n * 16 + r15;
        sc_[n] = nsc[col];
        sh_[n] = nsh[col];
      }
    }
    float sp[2] = {0.f, 0.f}, sq[2] = {0.f, 0.f};
#pragma unroll
    for (int m = 0; m < 4; m++) {
      int row = m0 + wm * 64 + m * 16 + g4 * 4;
#pragma unroll
      for (int n = 0; n < 2; n++) {
        int col = n0 + wn * 32 + n * 16 + r15;
#pragma unroll
        for (int j = 0; j < 4; j++) {
          float v = acc[m][n][j] + bb[n];
          float res = Rres[(size_t)(row + j) * 1024 + col];
          if (RESNORM) res = fmaf(res, sc_[n], sh_[n]);
          float r = v + res;
          Rout[(size_t)(row + j) * 1024 + col] = r;
          sp[n] += r;
          sq[n] = fmaf(r, r, sq[n]);
        }
      }
    }
#pragma unroll
    for (int n = 0; n < 2; n++) {
      sp[n] += __shfl_xor(sp[n], 16, 64);
      sp[n] += __shfl_xor(sp[n], 32, 64);
      sq[n] += __shfl_xor(sq[n], 16, 64);
      sq[n] += __shfl_xor(sq[n], 32, 64);
    }
    if (g4 == 0) {
      int slot = (by << 1) + wm;
#pragma unroll
      for (int n = 0; n < 2; n++) {
        int col = n0 + wn * 32 + n * 16 + r15;
        psum[(size_t)slot * 1024 + col] = sp[n];
        psumsq[(size_t)slot * 1024 + col] = sq[n];
      }
    }
    return;
  }

#pragma unroll
  for (int m = 0; m < 4; m++) {
    int row = m0 + wm * 64 + m * 16 + g4 * 4;
#pragma unroll
    for (int n = 0; n < 2; n++) {
      int col = n0 + wn * 32 + n * 16 + r15;
#pragma unroll
      for (int j = 0; j < 4; j++) {
        float v = acc[m][n][j];
        if (BIAS) v += bb[n];
        if (RELU) v = fmaxf(v, 0.f);
        if (OUTM == 1)      Cb[(size_t)(row + j) * ldc + col] = f2bf(v);
        else if (OUTM == 0) Cf[(size_t)(row + j) * ldc + col] = v;
      }
    }
  }
}

// ---------------------------------------------------------------------------
// Flash MFMA attention, double-buffered K/V staging with counted vmcnt.
// Grid (bh=128, qchunk=8); block = 64 q-rows (4 waves).
// qk: [4096][2048] bf16 (q|k slabs). Vt: [(b,h)][64][512] bf16.
// ---------------------------------------------------------------------------
__global__ __launch_bounds__(256, 2) void attn_k(
    const u16* __restrict__ qk, const u16* __restrict__ Vt,
    u16* __restrict__ o)
{
  __shared__ __align__(16) unsigned char Ks[2][16384];  // [128 s][128B dk] swz
  __shared__ __align__(16) unsigned char Vs[2][16384];  // [64 dk][256B s] swz
  __shared__ __align__(16) unsigned char Ps[16384];     // per-wave [16 q][256B s]

  const int bh  = blockIdx.x;
  const int qc  = blockIdx.y;
  const int b   = bh >> 4, h = bh & 15;
  const int tid = threadIdx.x;
  const int lane = tid & 63;
  const int wv   = tid >> 6;
  const int qcol = lane & 15;
  const int g    = lane >> 4;

  const size_t rowbase = (size_t)b * Tn;
  const size_t qrow0   = rowbase + qc * 64 + wv * 16;

  bf16x8 qf[2];
  {
    const u16* qp = &qk[(qrow0 + qcol) * 2048 + h * 64 + g * 8];
    qf[0] = *reinterpret_cast<const bf16x8*>(qp);
    qf[1] = *reinterpret_cast<const bf16x8*>(qp + 32);
  }

  f32x4 oa[4] = {};
  float m_run = -3e38f, l_run = 0.f;

  const int krow = tid >> 3, kch = tid & 7;
  const int vrow = tid >> 4, vch = tid & 15;
  unsigned char* Pw = &Ps[wv * 4096];

  auto stage_kv = [&](int c, int buf) {
#pragma unroll
    for (int i = 0; i < 4; i++) {
      int row = i * 32 + krow;
      const u16* gk = &qk[(rowbase + c * 128 + row) * 2048 + 1024 + h * 64
                          + ((kch ^ (row & 7)) << 3)];
      gl2lds16(gk, (char*)Ks[buf] + wv * 1024 + i * 4096);
    }
#pragma unroll
    for (int i = 0; i < 4; i++) {
      int row = i * 16 + vrow;
      const u16* gv = &Vt[(((size_t)bh * 64 + row) << 9) + c * 128
                          + ((vch ^ (row & 7)) << 3)];
      gl2lds16(gv, (char*)Vs[buf] + wv * 1024 + i * 4096);
    }
  };

  auto compute_c = [&](int cur) {
    // ---- QK^T: S^T tiles ----
    f32x4 sf[8];
#pragma unroll
    for (int t = 0; t < 8; t++) {
      sf[t] = (f32x4){0.f, 0.f, 0.f, 0.f};
      const int srow = t * 16 + qcol;
      const int base = srow * 128;
      const int sw = srow & 7;
#pragma unroll
      for (int ks = 0; ks < 2; ks++) {
        bf16x8 a = *reinterpret_cast<const bf16x8*>(
            &Ks[cur][base + (((ks * 4 + g) ^ sw) << 4)]);
        sf[t] = __builtin_amdgcn_mfma_f32_16x16x32_bf16(a, qf[ks], sf[t], 0, 0, 0);
      }
    }

    // ---- online softmax ----
    float mc = -3e38f;
#pragma unroll
    for (int t = 0; t < 8; t++)
#pragma unroll
      for (int r = 0; r < 4; r++) {
        float s = sf[t][r] * 0.125f;
        sf[t][r] = s;
        mc = fmaxf(mc, s);
      }
    mc = fmaxf(mc, __shfl_xor(mc, 16, 64));
    mc = fmaxf(mc, __shfl_xor(mc, 32, 64));
    float mnew = fmaxf(m_run, mc);
    float alpha = __expf(m_run - mnew);
    m_run = mnew;

    float lsum = 0.f;
#pragma unroll
    for (int t = 0; t < 8; t++)
#pragma unroll
      for (int r = 0; r < 4; r++) {
        float e = __expf(sf[t][r] - mnew);
        sf[t][r] = e;
        lsum += e;
      }
    lsum += __shfl_xor(lsum, 16, 64);
    lsum += __shfl_xor(lsum, 32, 64);
    l_run = l_run * alpha + lsum;

#pragma unroll
    for (int j = 0; j < 4; j++) {
      float av = __shfl(alpha, (g << 4) + g * 4 + j, 64);
#pragma unroll
      for (int nt = 0; nt < 4; nt++) oa[nt][j] *= av;
    }

    // ---- pack P -> per-wave LDS (swizzled), wave-coherent ----
#pragma unroll
    for (int t = 0; t < 8; t++) {
      int o0 = t * 32 + g * 8;
      int chunk = o0 >> 4;
      int sb = ((chunk ^ (qcol & 7)) << 4) | (o0 & 15);
      *reinterpret_cast<unsigned int*>(&Pw[qcol * 256 + sb]) =
          pack2bf(sf[t][0], sf[t][1]);
      *reinterpret_cast<unsigned int*>(&Pw[qcol * 256 + sb + 4]) =
          pack2bf(sf[t][2], sf[t][3]);
    }

    // ---- PV ----
    bf16x8 pa[4];
#pragma unroll
    for (int ks = 0; ks < 4; ks++)
      pa[ks] = *reinterpret_cast<const bf16x8*>(
          &Pw[qcol * 256 + (((ks * 4 + g) ^ (qcol & 7)) << 4)]);
#pragma unroll
    for (int nt = 0; nt < 4; nt++) {
      const int vr = nt * 16 + qcol;
      const int vsw = vr & 7;
#pragma unroll
      for (int ks = 0; ks < 4; ks++) {
        bf16x8 bvf = *reinterpret_cast<const bf16x8*>(
            &Vs[cur][vr * 256 + (((ks * 4 + g) ^ vsw) << 4)]);
        oa[nt] = __builtin_amdgcn_mfma_f32_16x16x32_bf16(pa[ks], bvf, oa[nt], 0, 0, 0);
      }
    }
  };

  stage_kv(0, 0);                    // 8 loads in flight
#pragma unroll 1
  for (int c = 0; c < 3; ++c) {
    stage_kv(c + 1, (c + 1) & 1);    // +8 -> 16 in flight
    WAITV(8);                        // chunk c landed; next chunk stays in flight
    hard_barrier();
    compute_c(c & 1);
    hard_barrier();                  // all waves done with buf (c&1)
  }
  WAITV(0);
  hard_barrier();
  compute_c(1);

  float rl = 1.f / l_run;
#pragma unroll
  for (int j = 0; j < 4; j++) {
    float il = __shfl(rl, (g << 4) + g * 4 + j, 64);
#pragma unroll
    for (int nt = 0; nt < 4; nt++)
      o[(qrow0 + g * 4 + j) * 1024 + h * 64 + nt * 16 + qcol] =
          f2bf(oa[nt][j] * il);
  }
}

// ---------------------------------------------------------------------------
__global__ __launch_bounds__(256) void reduce_stats_k(
    const float* __restrict__ ps, const float* __restrict__ pq,
    const float* __restrict__ g, const float* __restrict__ be,
    float* __restrict__ scale, float* __restrict__ shift)
{
  const int col = blockIdx.x * 256 + threadIdx.x;
  float s = 0.f, q = 0.f;
  for (int p = 0; p < 64; p++) {
    s += ps[(size_t)p * Dn + col];
    q += pq[(size_t)p * Dn + col];
  }
  const float invn = 1.f / 4096.f;
  float mean = s * invn;
  float var = q * invn - mean * mean;
  float inv = rsqrtf(var + 1e-3f);
  float sc = g[col] * inv;
  scale[col] = sc;
  shift[col] = be[col] - mean * sc;
}

// OUTMODE: 0 = fp32 only, 2 = bf16 only
template<int OUTMODE>
__global__ __launch_bounds__(256) void norm_k(
    const float* __restrict__ r, const float* __restrict__ scale,
    const float* __restrict__ shift, float* __restrict__ o, u16* __restrict__ ob)
{
  const size_t idx = (size_t)blockIdx.x * 256 + threadIdx.x;
  const int c4 = ((int)idx & 255) << 2;
  float4 rv = *reinterpret_cast<const float4*>(&r[idx << 2]);
  float4 sc = *reinterpret_cast<const float4*>(&scale[c4]);
  float4 sh = *reinterpret_cast<const float4*>(&shift[c4]);
  float4 ov = make_float4(fmaf(rv.x, sc.x, sh.x), fmaf(rv.y, sc.y, sh.y),
                          fmaf(rv.z, sc.z, sh.z), fmaf(rv.w, sc.w, sh.w));
  if (OUTMODE == 0) {
    *reinterpret_cast<float4*>(&o[idx << 2]) = ov;
  } else {
    uint2 p;
    p.x = pack2bf(ov.x, ov.y);
    p.y = pack2bf(ov.z, ov.w);
    *reinterpret_cast<uint2*>(&ob[idx << 2]) = p;
  }
}

// ---------------------------------------------------------------------------
extern "C" void kernel_launch(void* const* d_in, const int* in_sizes, int n_in,
                              void* d_out, int out_size, void* d_ws, size_t ws_size,
                              hipStream_t stream)
{
  const float* x   = (const float*)d_in[0];
  const float* wq  = (const float*)d_in[1];
  const float* wk  = (const float*)d_in[2];
  const float* wv  = (const float*)d_in[3];
  const float* W   = (const float*)d_in[4];
  const float* W1  = (const float*)d_in[5];
  const float* b1  = (const float*)d_in[6];
  const float* W2  = (const float*)d_in[7];
  const float* b2  = (const float*)d_in[8];
  const float* g1  = (const float*)d_in[9];
  const float* be1 = (const float*)d_in[10];
  const float* g2  = (const float*)d_in[11];
  const float* be2 = (const float*)d_in[12];

  float* out = (float*)d_out;
  float* ws  = (float*)d_ws;

  const size_t NB = (size_t)Mn * Dn;   // 4M
  float* ws1    = ws;                  // r1 (fp32)
  float* ws2    = ws1 + NB;            // r2 (fp32)
  float* psum   = ws2 + NB;            // 64*1024
  float* psumsq = psum + 64 * Dn;
  float* scale1 = psumsq + 64 * Dn;
  float* shift1 = scale1 + Dn;
  float* scale2 = shift1 + Dn;
  float* shift2 = scale2 + Dn;
  u16* xb      = (u16*)(shift2 + Dn);  // 4M
  u16* qkb     = xb + NB;              // 8M  [4096][2048]
  u16* vtb     = qkb + 2 * NB;         // 4M  [(b,h)][64][512]
  u16* concatb = vtb + NB;             // 4M
  u16* wqkvT   = concatb + NB;         // 3M
  u16* wt      = wqkvT + 3 * 1048576;
  u16* w1t     = wt + 1048576;
  u16* w2t     = w1t + 1048576;
  // aliases (qkb dead after attn):
  u16* out1b = qkb;
  u16* hb    = qkb + NB;

  dim3 b256(256), b512(512);

  // 0. converts / transposes
  cvt_bf16_k<<<dim3(2048), b256, 0, stream>>>(x, xb);
  tqkv_k<<<dim3(16, 48), b256, 0, stream>>>(wq, wk, wv, wqkvT);
  tw_k<<<dim3(16, 16, 3), b256, 0, stream>>>(W, W1, W2, wt, w1t, w2t);

  // 1. qkv = x @ [Wq|Wk|Wv]; q,k -> qkb (ldc 2048), V -> vtb transposed
  mgemm_k<0, 0, 1, 0, 1, 0><<<dim3(24, 32), b512, 0, stream>>>(
      xb, wqkvT, nullptr, nullptr, qkb, 2048,
      nullptr, nullptr, nullptr, nullptr, vtb, nullptr, nullptr);
  // 2. flash attention -> concat bf16
  attn_k<<<dim3(128, 8), b256, 0, stream>>>(qkb, vtb, concatb);
  // 3. r1 = x + concat @ W -> ws1 (+stats fused)
  mgemm_k<0, 0, 2, 1, 0, 0><<<dim3(8, 32), b512, 0, stream>>>(
      concatb, wt, nullptr, nullptr, nullptr, 1024,
      x, ws1, psum, psumsq, nullptr, nullptr, nullptr);
  reduce_stats_k<<<dim3(4), b256, 0, stream>>>(psum, psumsq, g1, be1, scale1, shift1);
  // 4. out1b = BN1(r1) bf16 (GEMM6 re-derives fp32 out1 on the fly)
  norm_k<2><<<dim3(NB / 1024), b256, 0, stream>>>(ws1, scale1, shift1, nullptr, out1b);
  // 5. h = relu(out1 @ W1 + b1) -> bf16
  mgemm_k<1, 1, 1, 0, 0, 0><<<dim3(8, 32), b512, 0, stream>>>(
      out1b, w1t, b1, nullptr, hb, 1024,
      nullptr, nullptr, nullptr, nullptr, nullptr, nullptr, nullptr);
  // 6. r2 = BN1(r1) + (h @ W2 + b2) -> ws2 (+stats fused)
  mgemm_k<1, 0, 2, 1, 0, 1><<<dim3(8, 32), b512, 0, stream>>>(
      hb, w2t, b2, nullptr, nullptr, 1024,
      ws1, ws2, psum, psumsq, nullptr, scale1, shift1);
  reduce_stats_k<<<dim3(4), b256, 0, stream>>>(psum, psumsq, g2, be2, scale2, shift2);
  // 7. final BN -> d_out
  norm_k<0><<<dim3(NB / 1024), b256, 0, stream>>>(ws2, scale2, shift2, out, nullptr);
}